// Round 10
// baseline (722.572 us; speedup 1.0000x reference)
//
#include <hip/hip_runtime.h>
#include <hip/hip_bf16.h>
#include <hip/hip_cooperative_groups.h>
#include <cstdint>
#include <cstddef>

namespace cg = cooperative_groups;

#define NN 100000      // nodes
#define NE 1600000     // edges
#define HH 128         // hidden dim
#define NG 256         // graphs

#define NB 196         // buckets (512 nodes each; 196*512 = 100352 >= NN)
#define BSH 9          // bucket shift
#define BMSK 511
#define ECH 8164       // edges per chunk: 196*8164 >= NE

typedef __bf16 bf16x8 __attribute__((ext_vector_type(8)));
typedef float floatx4 __attribute__((ext_vector_type(4)));

__device__ __forceinline__ uint32_t f2b(float f) {
  union { float f; uint32_t u; } v; v.f = f;
  uint32_t u = v.u;
  return (u + 0x7FFFu + ((u >> 16) & 1u)) >> 16;   // RNE to bf16 (raw 16 bits)
}
__device__ __forceinline__ float b2f(uint32_t h) {
  union { uint32_t u; float f; } v; v.u = h << 16;
  return v.f;
}
__device__ __forceinline__ void addrow(float* a, uint4 v) {
  a[0] += b2f(v.x & 0xFFFFu); a[1] += b2f(v.x >> 16);
  a[2] += b2f(v.y & 0xFFFFu); a[3] += b2f(v.y >> 16);
  a[4] += b2f(v.z & 0xFFFFu); a[5] += b2f(v.z >> 16);
  a[6] += b2f(v.w & 0xFFFFu); a[7] += b2f(v.w >> 16);
}

// ================= cooperative CSR build + node prep (replaces 13 dispatches) =================
struct BuildArgs {
  const int* src; const int* dst; const int* batch;
  int* blkcntA; int* poffA; int* colsumA; int* gbaseA;
  uint2* pairsA;
  int* blkcntB; int* poffB; int* colsumB; int* gbaseB;
  uint32_t* pairB;
  int* off; float* inv; int* csrs;
  int* dhist2; int* dcur; int* order; int* gstart;
};

__global__ __launch_bounds__(256) void k_build(BuildArgs A) {
  cg::grid_group grid = cg::this_grid();
  __shared__ int sm[1536];   // aliased per phase (max: bucket_sort 1280 ints)
  const int b = blockIdx.x, t = threadIdx.x;

  // P1: cntA — src-bucket histogram per edge chunk
  {
    int* h = sm;
    if (t < NB) h[t] = 0;
    __syncthreads();
    int e0 = b * ECH, e1 = min(e0 + ECH, NE);
    for (int i = e0 + t; i < e1; i += 256) atomicAdd(&h[A.src[i] >> BSH], 1);
    __syncthreads();
    if (t < NB) A.blkcntA[b * NB + t] = h[t];
  }
  grid.sync();
  // P2: colscanA — block b scans its bucket column over 196 chunks
  {
    int* s = sm;
    int x = (t < NB) ? A.blkcntA[t * NB + b] : 0;
    s[t] = x; __syncthreads();
    for (int d = 1; d < 256; d <<= 1) {
      int v = (t >= d) ? s[t - d] : 0; __syncthreads(); s[t] += v; __syncthreads();
    }
    if (t < NB) A.poffA[t * NB + b] = s[t] - x;
    if (t == 255) A.colsumA[b] = s[255];
  }
  grid.sync();
  // P3: gscanA — block 0
  if (b == 0) {
    int* s = sm;
    int x = (t < NB) ? A.colsumA[t] : 0;
    s[t] = x; __syncthreads();
    for (int d = 1; d < 256; d <<= 1) {
      int v = (t >= d) ? s[t - d] : 0; __syncthreads(); s[t] += v; __syncthreads();
    }
    if (t < NB) A.gbaseA[t] = s[t] - x;
    if (t == 0) A.gbaseA[NB] = NE;
  }
  grid.sync();
  // P4: placeA — src-bucket-contiguous (src,dst) pairs
  {
    int* cur = sm;
    if (t < NB) cur[t] = A.poffA[b * NB + t] + A.gbaseA[t];
    __syncthreads();
    int e0 = b * ECH, e1 = min(e0 + ECH, NE);
    for (int i = e0 + t; i < e1; i += 256) {
      int s_ = A.src[i], d_ = A.dst[i];
      int p = atomicAdd(&cur[s_ >> BSH], 1);
      A.pairsA[p] = make_uint2((unsigned)s_, (unsigned)d_);
    }
  }
  grid.sync();
  // P5: cntB — dst-bucket histogram over pairsA chunks
  {
    int* h = sm;
    if (t < NB) h[t] = 0;
    __syncthreads();
    int e0 = b * ECH, e1 = min(e0 + ECH, NE);
    for (int i = e0 + t; i < e1; i += 256) atomicAdd(&h[A.pairsA[i].y >> BSH], 1);
    __syncthreads();
    if (t < NB) A.blkcntB[b * NB + t] = h[t];
  }
  grid.sync();
  // P6: colscanB
  {
    int* s = sm;
    int x = (t < NB) ? A.blkcntB[t * NB + b] : 0;
    s[t] = x; __syncthreads();
    for (int d = 1; d < 256; d <<= 1) {
      int v = (t >= d) ? s[t - d] : 0; __syncthreads(); s[t] += v; __syncthreads();
    }
    if (t < NB) A.poffB[t * NB + b] = s[t] - x;
    if (t == 255) A.colsumB[b] = s[255];
  }
  grid.sync();
  // P7: gscanB
  if (b == 0) {
    int* s = sm;
    int x = (t < NB) ? A.colsumB[t] : 0;
    s[t] = x; __syncthreads();
    for (int d = 1; d < 256; d <<= 1) {
      int v = (t >= d) ? s[t - d] : 0; __syncthreads(); s[t] += v; __syncthreads();
    }
    if (t < NB) A.gbaseB[t] = s[t] - x;
    if (t == 0) { A.gbaseB[NB] = NE; A.off[NN] = NE; }
  }
  grid.sync();
  // P8: placeB — dst-bucket-contiguous packed (src | dstlow<<17), stable (src-order kept)
  {
    int* cur = sm;
    if (t < NB) cur[t] = A.poffB[b * NB + t] + A.gbaseB[t];
    __syncthreads();
    int e0 = b * ECH, e1 = min(e0 + ECH, NE);
    for (int i = e0 + t; i < e1; i += 256) {
      uint2 v = A.pairsA[i];
      int p = atomicAdd(&cur[v.y >> BSH], 1);
      A.pairB[p] = v.x | ((v.y & (unsigned)BMSK) << 17);
    }
  }
  grid.sync();
  // P9: per-bucket counting sort -> off, inv, csrs; fused degree-hist + gstart
  {
    int* cnt = sm; int* loff = sm + 512; int* psum = sm + 1024;
    cnt[t] = 0; cnt[t + 256] = 0;
    __syncthreads();
    int s0 = A.gbaseB[b], s1 = A.gbaseB[b + 1];
    for (int i = s0 + t; i < s1; i += 256) atomicAdd(&cnt[A.pairB[i] >> 17], 1);
    __syncthreads();
    int a0 = cnt[2 * t], a1 = cnt[2 * t + 1];
    int s = a0 + a1;
    psum[t] = s; __syncthreads();
    for (int d = 1; d < 256; d <<= 1) {
      int v = (t >= d) ? psum[t - d] : 0; __syncthreads(); psum[t] += v; __syncthreads();
    }
    int excl = psum[t] - s;
    loff[2 * t] = excl;
    loff[2 * t + 1] = excl + a0;
    __syncthreads();
    int* h64 = psum;             // psum dead now
    if (t < 64) h64[t] = 0;
    __syncthreads();
#pragma unroll
    for (int k = 0; k < 2; ++k) {
      int i = t + k * 256;
      int node = b * 512 + i;
      if (node < NN) {
        A.off[node] = s0 + loff[i];
        A.inv[node] = rsqrtf((float)cnt[i] + 1.0f);
        int d = cnt[i]; if (d > 63) d = 63;
        atomicAdd(&h64[d], 1);
      }
    }
    __syncthreads();
    if (t < 64) A.dhist2[b * 64 + t] = h64[t];
    // gstart for this block's node range (batch sorted)
    int n0 = b * 512, n1 = min(n0 + 512, NN);
    for (int i = n0 + t; i < n1; i += 256) {
      int bb = A.batch[i];
      if (i == 0) { for (int g = 0; g <= bb; ++g) A.gstart[g] = 0; }
      else { int aa = A.batch[i - 1]; for (int g = aa + 1; g <= bb; ++g) A.gstart[g] = i; }
      if (i == NN - 1) { for (int g = bb + 1; g <= NG; ++g) A.gstart[g] = NN; }
    }
    __syncthreads();
    cnt[t] = loff[t]; cnt[t + 256] = loff[t + 256];   // counters -> cursors
    __syncthreads();
    for (int i = s0 + t; i < s1; i += 256) {
      uint32_t v = A.pairB[i];
      int p = atomicAdd(&cnt[v >> 17], 1);
      A.csrs[s0 + p] = (int)(v & 0x1FFFFu);
    }
  }
  grid.sync();
  // P10: dscan — block 0 wave 0: sum dhist2 columns, descending exclusive scan (LPT)
  if (b == 0 && t < 64) {
    int sum = 0;
    for (int r = 0; r < NB; ++r) sum += A.dhist2[r * 64 + (63 - t)];
    int v = sum;
    for (int d = 1; d < 64; d <<= 1) { int u = __shfl_up(v, d); if (t >= d) v += u; }
    A.dcur[63 - t] = v - sum;
  }
  grid.sync();
  // P11: dplace — block b places its 512 nodes into LPT order
  {
    int* h = sm; int* base = sm + 64;
    if (t < 64) h[t] = 0;
    __syncthreads();
    int dd[2], ld[2];
    int n0 = b * 512;
#pragma unroll
    for (int k = 0; k < 2; ++k) {
      int i = n0 + t + k * 256;
      dd[k] = -1; ld[k] = 0;
      if (i < NN) {
        int d = A.off[i + 1] - A.off[i]; if (d > 63) d = 63;
        dd[k] = d;
        ld[k] = atomicAdd(&h[d], 1);
      }
    }
    __syncthreads();
    if (t < 64) base[t] = h[t] ? atomicAdd(&A.dcur[t], h[t]) : 0;
    __syncthreads();
#pragma unroll
    for (int k = 0; k < 2; ++k) {
      int i = n0 + t + k * 256;
      if (i < NN) A.order[base[dd[k]] + ld[k]] = i;
    }
  }
}

// ================= GEMM: Out[M,128] = bf16( scale[r] * (relu?(A@W + bias)) ) =================
__global__ __launch_bounds__(256) void k_gemm(
    const uint16_t* __restrict__ A16, const float* __restrict__ A32,
    const float* __restrict__ W, const float* __restrict__ bias,
    const float* __restrict__ scale,      // nullptr or per-row scale (inv)
    uint16_t* __restrict__ Out, int M, int do_relu)
{
  __shared__ uint16_t Wt[128][136];
  const int tid = threadIdx.x;

  for (int it = 0; it < 16; ++it) {
    int idx = tid + it * 256;
    int n = idx & 127;
    int k0 = (idx >> 7) * 4;
    uint2 wv;
    wv.x = f2b(W[(k0 + 0) * 128 + n]) | (f2b(W[(k0 + 1) * 128 + n]) << 16);
    wv.y = f2b(W[(k0 + 2) * 128 + n]) | (f2b(W[(k0 + 3) * 128 + n]) << 16);
    *(uint2*)&Wt[n][k0] = wv;
  }
  __syncthreads();

  const int lane = tid & 63;
  const int wave = tid >> 6;
  const int lrow = lane & 15;
  const int lk = (lane >> 4) * 8;
  const int row0 = blockIdx.x * 128 + wave * 32;

  floatx4 acc[2][8];
#pragma unroll
  for (int t = 0; t < 2; ++t)
#pragma unroll
    for (int n = 0; n < 8; ++n)
      acc[t][n] = (floatx4){0.f, 0.f, 0.f, 0.f};

#pragma unroll
  for (int ks = 0; ks < 4; ++ks) {
    bf16x8 a[2];
#pragma unroll
    for (int t = 0; t < 2; ++t) {
      int r = row0 + t * 16 + lrow;
      uint4 tmp = {0u, 0u, 0u, 0u};
      if (r < M) {
        if (A32) {
          float4 f0 = *(const float4*)(A32 + (size_t)r * HH + ks * 32 + lk);
          float4 f1 = *(const float4*)(A32 + (size_t)r * HH + ks * 32 + lk + 4);
          tmp.x = f2b(f0.x) | (f2b(f0.y) << 16);
          tmp.y = f2b(f0.z) | (f2b(f0.w) << 16);
          tmp.z = f2b(f1.x) | (f2b(f1.y) << 16);
          tmp.w = f2b(f1.z) | (f2b(f1.w) << 16);
        } else {
          tmp = *(const uint4*)(A16 + (size_t)r * HH + ks * 32 + lk);
        }
      }
      a[t] = __builtin_bit_cast(bf16x8, tmp);
    }
#pragma unroll
    for (int n = 0; n < 8; ++n) {
      bf16x8 b = __builtin_bit_cast(bf16x8, *(const uint4*)&Wt[n * 16 + lrow][ks * 32 + lk]);
      acc[0][n] = __builtin_amdgcn_mfma_f32_16x16x32_bf16(a[0], b, acc[0][n], 0, 0, 0);
      acc[1][n] = __builtin_amdgcn_mfma_f32_16x16x32_bf16(a[1], b, acc[1][n], 0, 0, 0);
    }
  }

  float bc[8];
#pragma unroll
  for (int n = 0; n < 8; ++n) bc[n] = bias[n * 16 + lrow];

  const int rbase = (lane >> 4) * 4;
#pragma unroll
  for (int t = 0; t < 2; ++t) {
#pragma unroll
    for (int r = 0; r < 4; ++r) {
      int row = row0 + t * 16 + rbase + r;
      if (row < M) {
        float sc = scale ? scale[row] : 1.0f;
#pragma unroll
        for (int n = 0; n < 8; ++n) {
          float v = acc[t][n][r] + bc[n];
          if (do_relu) v = fmaxf(v, 0.f);
          v *= sc;
          Out[(size_t)row * HH + n * 16 + lrow] = (uint16_t)f2b(v);
        }
      }
    }
  }
}

// ================= aggregation: pre-scaled rows, pure gather-sum, unroll-4 =================
__global__ __launch_bounds__(256) void k_agg(
    const uint16_t* __restrict__ hw2, const int* __restrict__ off,
    const int* __restrict__ csrs, const float* __restrict__ inv,
    const int* __restrict__ order,
    uint16_t* __restrict__ hout, int do_relu)
{
  int slot = blockIdx.x * 16 + (threadIdx.x >> 4);
  if (slot >= NN) return;
  int node = order[slot];
  int c = (threadIdx.x & 15) * 8;   // 8 channels = 16 B per lane

  uint4 sv = *(const uint4*)(hw2 + (size_t)node * HH + c);
  float a[8] = {0.f, 0.f, 0.f, 0.f, 0.f, 0.f, 0.f, 0.f};
  addrow(a, sv);                    // self term (already inv[node]-scaled)

  int e0 = off[node], e1 = off[node + 1];
  int e = e0;
  for (; e + 4 <= e1; e += 4) {
    int s0 = csrs[e + 0], s1 = csrs[e + 1], s2 = csrs[e + 2], s3 = csrs[e + 3];
    uint4 v0 = *(const uint4*)(hw2 + (size_t)s0 * HH + c);
    uint4 v1 = *(const uint4*)(hw2 + (size_t)s1 * HH + c);
    uint4 v2 = *(const uint4*)(hw2 + (size_t)s2 * HH + c);
    uint4 v3 = *(const uint4*)(hw2 + (size_t)s3 * HH + c);
    addrow(a, v0); addrow(a, v1); addrow(a, v2); addrow(a, v3);
  }
  for (; e < e1; ++e) {
    int s = csrs[e];
    uint4 v = *(const uint4*)(hw2 + (size_t)s * HH + c);
    addrow(a, v);
  }
  float invd = inv[node];
#pragma unroll
  for (int j = 0; j < 8; ++j) {
    a[j] *= invd;
    if (do_relu) a[j] = fmaxf(a[j], 0.f);
  }
  uint4 o;
  o.x = f2b(a[0]) | (f2b(a[1]) << 16);
  o.y = f2b(a[2]) | (f2b(a[3]) << 16);
  o.z = f2b(a[4]) | (f2b(a[5]) << 16);
  o.w = f2b(a[6]) | (f2b(a[7]) << 16);
  *(uint4*)(hout + (size_t)node * HH + c) = o;
}

// ================= fused pool + decoder: one block per graph, zero atomics =================
__global__ __launch_bounds__(256) void k_pooldec(
    const uint16_t* __restrict__ h, const int* __restrict__ gstart,
    const float* __restrict__ w1, const float* __restrict__ b1,
    const float* __restrict__ w2, const float* __restrict__ b2,
    float* __restrict__ out)
{
  __shared__ float red[16][132];   // +4 pad
  __shared__ float p[128], tmpv[128];
  int g = blockIdx.x;
  int tid = threadIdx.x;
  int slot = tid >> 4;
  int c = (tid & 15) * 8;

  int r0 = gstart[g], r1 = gstart[g + 1];
  float a[8] = {0.f, 0.f, 0.f, 0.f, 0.f, 0.f, 0.f, 0.f};
  for (int r = r0 + slot; r < r1; r += 16) {
    uint4 v = *(const uint4*)(h + (size_t)r * HH + c);
    a[0] += b2f(v.x & 0xFFFFu); a[1] += b2f(v.x >> 16);
    a[2] += b2f(v.y & 0xFFFFu); a[3] += b2f(v.y >> 16);
    a[4] += b2f(v.z & 0xFFFFu); a[5] += b2f(v.z >> 16);
    a[6] += b2f(v.w & 0xFFFFu); a[7] += b2f(v.w >> 16);
  }
  *(float4*)&red[slot][c]     = make_float4(a[0], a[1], a[2], a[3]);
  *(float4*)&red[slot][c + 4] = make_float4(a[4], a[5], a[6], a[7]);
  __syncthreads();
  if (tid < 128) {
    float s = 0.f;
#pragma unroll
    for (int k = 0; k < 16; ++k) s += red[k][tid];
    p[tid] = s;
  }
  __syncthreads();
  if (tid < 128) {
    float acc1 = b1[tid];
    for (int k = 0; k < 128; ++k) acc1 += p[k] * w1[k * 128 + tid];
    tmpv[tid] = fmaxf(acc1, 0.f);
  }
  __syncthreads();
  if (tid < 10) {
    float o = b2[tid];
    for (int k = 0; k < 128; ++k) o += tmpv[k] * w2[k * 10 + tid];
    out[g * 10 + tid] = o;
  }
}

extern "C" void kernel_launch(void* const* d_in, const int* in_sizes, int n_in,
                              void* d_out, int out_size, void* d_ws, size_t ws_size,
                              hipStream_t stream) {
  const float* x       = (const float*)d_in[0];
  const int*   eidx    = (const int*)d_in[1];
  const int*   src     = eidx;            // edge_index[0]
  const int*   dst     = eidx + NE;       // edge_index[1]
  const int*   batch   = (const int*)d_in[3];
  const float* enc_w1  = (const float*)d_in[4];
  const float* enc_b1  = (const float*)d_in[5];
  const float* enc_w2  = (const float*)d_in[6];
  const float* enc_b2  = (const float*)d_in[7];
  const float* conv_w  = (const float*)d_in[8];
  const float* conv_b  = (const float*)d_in[9];
  const float* dec_w1  = (const float*)d_in[10];
  const float* dec_b1  = (const float*)d_in[11];
  const float* dec_w2  = (const float*)d_in[12];
  const float* dec_b2  = (const float*)d_in[13];
  float* out = (float*)d_out;

  char* ws = (char*)d_ws;
  size_t o = 0;
  auto alloc = [&](size_t bytes) -> char* {
    char* p = ws + o;
    o += (bytes + 255) & ~(size_t)255;
    return p;
  };
  int*      off     = (int*)alloc((size_t)(NN + 1) * 4);
  int*      csrs    = (int*)alloc((size_t)NE * 4);
  float*    inv     = (float*)alloc((size_t)NN * 4);
  int*      blkcntA = (int*)alloc((size_t)NB * NB * 4);
  int*      poffA   = (int*)alloc((size_t)NB * NB * 4);
  int*      blkcntB = (int*)alloc((size_t)NB * NB * 4);
  int*      poffB   = (int*)alloc((size_t)NB * NB * 4);
  int*      colsumA = (int*)alloc((size_t)NB * 4);
  int*      colsumB = (int*)alloc((size_t)NB * 4);
  int*      gbaseA  = (int*)alloc((size_t)(NB + 1) * 4);
  int*      gbaseB  = (int*)alloc((size_t)(NB + 1) * 4);
  int*      dhist2  = (int*)alloc((size_t)NB * 64 * 4);
  int*      dcur    = (int*)alloc(64 * 4);
  int*      order   = (int*)alloc((size_t)NN * 4);
  int*      gstart  = (int*)alloc((size_t)(NG + 1) * 4);
  uint16_t* buf0    = (uint16_t*)alloc((size_t)NN * HH * 2);
  uint16_t* buf1    = (uint16_t*)alloc((size_t)NN * HH * 2);
  uint2*    pairsA  = (uint2*)buf1;                          // 12.8 MB, dead before encoder
  uint32_t* pairB   = (uint32_t*)((char*)buf1 + (size_t)NE * 8);  // +6.4 MB, still < 25.6 MB

  // single cooperative kernel: full CSR build + degree-LPT order + graph bounds
  BuildArgs ba;
  ba.src = src; ba.dst = dst; ba.batch = batch;
  ba.blkcntA = blkcntA; ba.poffA = poffA; ba.colsumA = colsumA; ba.gbaseA = gbaseA;
  ba.pairsA = pairsA;
  ba.blkcntB = blkcntB; ba.poffB = poffB; ba.colsumB = colsumB; ba.gbaseB = gbaseB;
  ba.pairB = pairB;
  ba.off = off; ba.inv = inv; ba.csrs = csrs;
  ba.dhist2 = dhist2; ba.dcur = dcur; ba.order = order; ba.gstart = gstart;
  void* bargs[] = { &ba };
  hipLaunchCooperativeKernel((void*)k_build, dim3(NB), dim3(256), bargs, 0, stream);

  // encoder (first GEMM reads fp32 x directly)
  const int GB = (NN + 127) / 128;   // 782
  k_gemm<<<dim3(GB), dim3(256), 0, stream>>>(nullptr, x, enc_w1, enc_b1, nullptr, buf1, NN, 1);
  k_gemm<<<dim3(GB), dim3(256), 0, stream>>>(buf1, nullptr, enc_w2, enc_b2, nullptr, buf0, NN, 0);

  // 3 GCN layers: conv GEMM writes inv[r]-pre-scaled rows; agg is pure gather-sum
  const int AB = (NN + 15) / 16;   // 6250
  k_gemm<<<dim3(GB), dim3(256), 0, stream>>>(buf0, nullptr, conv_w + 0 * 16384, conv_b + 0,   inv, buf1, NN, 0);
  k_agg <<<dim3(AB), dim3(256), 0, stream>>>(buf1, off, csrs, inv, order, buf0, 1);
  k_gemm<<<dim3(GB), dim3(256), 0, stream>>>(buf0, nullptr, conv_w + 1 * 16384, conv_b + 128, inv, buf1, NN, 0);
  k_agg <<<dim3(AB), dim3(256), 0, stream>>>(buf1, off, csrs, inv, order, buf0, 1);
  k_gemm<<<dim3(GB), dim3(256), 0, stream>>>(buf0, nullptr, conv_w + 2 * 16384, conv_b + 256, inv, buf1, NN, 0);
  k_agg <<<dim3(AB), dim3(256), 0, stream>>>(buf1, off, csrs, inv, order, buf0, 0);

  // fused pool + decoder
  k_pooldec<<<dim3(NG), dim3(256), 0, stream>>>(buf0, gstart, dec_w1, dec_b1, dec_w2, dec_b2, out);
}

// Round 11
// 544.597 us; speedup vs baseline: 1.3268x; 1.3268x over previous
//
#include <hip/hip_runtime.h>
#include <hip/hip_bf16.h>
#include <cstdint>
#include <cstddef>

#define NN 100000      // nodes
#define NE 1600000     // edges
#define HH 128         // hidden dim
#define NG 256         // graphs

#define NB 196         // buckets (512 nodes each; 196*512 = 100352 >= NN)
#define BSH 9          // bucket shift
#define BMSK 511
#define CHUNK 16384    // edges per binning block
#define NBLK 98        // ceil(NE / CHUNK)

typedef __bf16 bf16x8 __attribute__((ext_vector_type(8)));
typedef float floatx4 __attribute__((ext_vector_type(4)));

__device__ __forceinline__ uint32_t f2b(float f) {
  union { float f; uint32_t u; } v; v.f = f;
  uint32_t u = v.u;
  return (u + 0x7FFFu + ((u >> 16) & 1u)) >> 16;   // RNE to bf16 (raw 16 bits)
}
__device__ __forceinline__ float b2f(uint32_t h) {
  union { uint32_t u; float f; } v; v.u = h << 16;
  return v.f;
}
__device__ __forceinline__ void addrow(float* a, uint4 v) {
  a[0] += b2f(v.x & 0xFFFFu); a[1] += b2f(v.x >> 16);
  a[2] += b2f(v.y & 0xFFFFu); a[3] += b2f(v.y >> 16);
  a[4] += b2f(v.z & 0xFFFFu); a[5] += b2f(v.z >> 16);
  a[6] += b2f(v.w & 0xFFFFu); a[7] += b2f(v.w >> 16);
}

// ================= CSR build: src-bucket sort, then dst-bucket counting sort =================

__global__ __launch_bounds__(256) void k_cntA(const int* __restrict__ src,
                                              int* __restrict__ blkcnt) {
  __shared__ int h[NB];
  int t = threadIdx.x;
  if (t < NB) h[t] = 0;
  __syncthreads();
  int base = blockIdx.x * CHUNK, end = min(base + CHUNK, NE);
  for (int i = base + t; i < end; i += 256) atomicAdd(&h[src[i] >> BSH], 1);
  __syncthreads();
  if (t < NB) blkcnt[blockIdx.x * NB + t] = h[t];
}

__global__ __launch_bounds__(256) void k_cntB(const uint2* __restrict__ pairs,
                                              int* __restrict__ blkcnt) {
  __shared__ int h[NB];
  int t = threadIdx.x;
  if (t < NB) h[t] = 0;
  __syncthreads();
  int base = blockIdx.x * CHUNK, end = min(base + CHUNK, NE);
  for (int i = base + t; i < end; i += 256) atomicAdd(&h[pairs[i].y >> BSH], 1);
  __syncthreads();
  if (t < NB) blkcnt[blockIdx.x * NB + t] = h[t];
}

__global__ __launch_bounds__(64) void k_colscan(const int* __restrict__ blkcnt,
                                                int* __restrict__ poff,
                                                int* __restrict__ colsum) {
  int b = blockIdx.x, t = threadIdx.x;
  int carry = 0;
  for (int base = 0; base < NBLK; base += 64) {
    int r = base + t;
    int x = (r < NBLK) ? blkcnt[r * NB + b] : 0;
    int v = x;
    for (int d = 1; d < 64; d <<= 1) { int u = __shfl_up(v, d); if (t >= d) v += u; }
    if (r < NBLK) poff[r * NB + b] = carry + v - x;
    carry += __shfl(v, 63);
  }
  if (t == 0) colsum[b] = carry;
}

__global__ void k_gscan(const int* __restrict__ colsum, int* __restrict__ gbase,
                        int* __restrict__ off, int set_off) {
  __shared__ int s[256];
  int t = threadIdx.x;
  int x = (t < NB) ? colsum[t] : 0;
  s[t] = x; __syncthreads();
  for (int d = 1; d < 256; d <<= 1) {
    int v = (t >= d) ? s[t - d] : 0;
    __syncthreads();
    s[t] += v;
    __syncthreads();
  }
  if (t < NB) gbase[t] = s[t] - x;
  if (t == 0) { gbase[NB] = NE; if (set_off) off[NN] = NE; }
}

__global__ __launch_bounds__(256) void k_placeA(const int* __restrict__ src,
                                                const int* __restrict__ dst,
                                                const int* __restrict__ poff,
                                                const int* __restrict__ gbase,
                                                uint2* __restrict__ pairs) {
  __shared__ int cur[NB];
  int t = threadIdx.x;
  if (t < NB) cur[t] = poff[blockIdx.x * NB + t] + gbase[t];
  __syncthreads();
  int base = blockIdx.x * CHUNK, end = min(base + CHUNK, NE);
  for (int i = base + t; i < end; i += 256) {
    int s = src[i], d = dst[i];
    int p = atomicAdd(&cur[s >> BSH], 1);
    pairs[p] = make_uint2((unsigned)s, (unsigned)d);
  }
}

__global__ __launch_bounds__(256) void k_placeB(const uint2* __restrict__ pairs,
                                                const int* __restrict__ poff,
                                                const int* __restrict__ gbase,
                                                uint32_t* __restrict__ outb) {
  __shared__ int cur[NB];
  int t = threadIdx.x;
  if (t < NB) cur[t] = poff[blockIdx.x * NB + t] + gbase[t];
  __syncthreads();
  int base = blockIdx.x * CHUNK, end = min(base + CHUNK, NE);
  for (int i = base + t; i < end; i += 256) {
    uint2 v = pairs[i];
    int p = atomicAdd(&cur[v.y >> BSH], 1);
    outb[p] = v.x | ((v.y & (unsigned)BMSK) << 17);
  }
}

// per-dst-bucket counting sort -> off/inv/csrs; fused per-block degree hist + gstart
__global__ __launch_bounds__(256) void k_bucket_sort(
    const uint32_t* __restrict__ pairbuf, const int* __restrict__ gbase,
    const int* __restrict__ batch,
    int* __restrict__ off, float* __restrict__ inv, int* __restrict__ csrs,
    int* __restrict__ dhist2, int* __restrict__ gstart)
{
  __shared__ int cnt[512];
  __shared__ int loff[512];
  __shared__ int psum[256];
  int b = blockIdx.x;
  int tid = threadIdx.x;
  cnt[tid] = 0; cnt[tid + 256] = 0;
  __syncthreads();
  int s0 = gbase[b], s1 = gbase[b + 1];
  for (int i = s0 + tid; i < s1; i += 256)
    atomicAdd(&cnt[pairbuf[i] >> 17], 1);
  __syncthreads();
  int a0 = cnt[2 * tid], a1 = cnt[2 * tid + 1];
  int s = a0 + a1;
  psum[tid] = s;
  __syncthreads();
  for (int d = 1; d < 256; d <<= 1) {
    int v = (tid >= d) ? psum[tid - d] : 0;
    __syncthreads();
    psum[tid] += v;
    __syncthreads();
  }
  int excl = psum[tid] - s;
  loff[2 * tid] = excl;
  loff[2 * tid + 1] = excl + a0;
  __syncthreads();
  int* h64 = psum;               // psum dead after excl computed
  if (tid < 64) h64[tid] = 0;
  __syncthreads();
#pragma unroll
  for (int k = 0; k < 2; ++k) {
    int i = tid + k * 256;
    int node = b * 512 + i;
    if (node < NN) {
      off[node] = s0 + loff[i];
      inv[node] = rsqrtf((float)cnt[i] + 1.0f);
      int d = cnt[i]; if (d > 63) d = 63;
      atomicAdd(&h64[d], 1);
    }
  }
  // gstart for this block's node range (batch sorted)
  {
    int n0 = b * 512, n1 = min(n0 + 512, NN);
    for (int i = n0 + tid; i < n1; i += 256) {
      int bb = batch[i];
      if (i == 0) { for (int g = 0; g <= bb; ++g) gstart[g] = 0; }
      else { int aa = batch[i - 1]; for (int g = aa + 1; g <= bb; ++g) gstart[g] = i; }
      if (i == NN - 1) { for (int g = bb + 1; g <= NG; ++g) gstart[g] = NN; }
    }
  }
  __syncthreads();
  if (tid < 64) dhist2[b * 64 + tid] = h64[tid];
  cnt[tid] = loff[tid]; cnt[tid + 256] = loff[tid + 256];   // counters -> cursors
  __syncthreads();
  for (int i = s0 + tid; i < s1; i += 256) {
    uint32_t v = pairbuf[i];
    int p = atomicAdd(&cnt[v >> 17], 1);
    csrs[s0 + p] = (int)(v & 0x1FFFFu);
  }
}

// ================= degree order: column-sum of dhist2 + descending scan (LPT) =================
__global__ void k_dscan(const int* __restrict__ dhist2, int* __restrict__ dcur) {
  int t = threadIdx.x;             // 64 threads
  int sum = 0;
  for (int r = 0; r < NB; ++r) sum += dhist2[r * 64 + (63 - t)];
  int v = sum;
  for (int d = 1; d < 64; d <<= 1) { int u = __shfl_up(v, d); if (t >= d) v += u; }
  dcur[63 - t] = v - sum;
}

__global__ __launch_bounds__(256) void k_dplace(const int* __restrict__ off,
                                                int* __restrict__ dcur,
                                                int* __restrict__ order) {
  __shared__ int h[64], base[64];
  int t = threadIdx.x;
  if (t < 64) h[t] = 0;
  __syncthreads();
  int i = blockIdx.x * 256 + t;
  int d = 0, ld = 0;
  if (i < NN) { d = off[i + 1] - off[i]; if (d > 63) d = 63; ld = atomicAdd(&h[d], 1); }
  __syncthreads();
  if (t < 64) base[t] = h[t] ? atomicAdd(&dcur[t], h[t]) : 0;
  __syncthreads();
  if (i < NN) order[base[d] + ld] = i;
}

// ================= GEMM: Out[M,128] = bf16( scale[r] * (relu?(A@W + bias)) ) =================
// Vectorized epilogue: acc -> LDS transpose (reusing Wt) -> uint4 stores (8/thread vs 64).
__global__ __launch_bounds__(256) void k_gemm(
    const uint16_t* __restrict__ A16, const float* __restrict__ A32,
    const float* __restrict__ W, const float* __restrict__ bias,
    const float* __restrict__ scale,      // nullptr or per-row scale (inv)
    uint16_t* __restrict__ Out, int M, int do_relu)
{
  __shared__ uint16_t Wt[128][136];
  const int tid = threadIdx.x;

  for (int it = 0; it < 16; ++it) {
    int idx = tid + it * 256;
    int n = idx & 127;
    int k0 = (idx >> 7) * 4;
    uint2 wv;
    wv.x = f2b(W[(k0 + 0) * 128 + n]) | (f2b(W[(k0 + 1) * 128 + n]) << 16);
    wv.y = f2b(W[(k0 + 2) * 128 + n]) | (f2b(W[(k0 + 3) * 128 + n]) << 16);
    *(uint2*)&Wt[n][k0] = wv;
  }
  __syncthreads();

  const int lane = tid & 63;
  const int wave = tid >> 6;
  const int lrow = lane & 15;
  const int lk = (lane >> 4) * 8;
  const int row0 = blockIdx.x * 128 + wave * 32;

  floatx4 acc[2][8];
#pragma unroll
  for (int t = 0; t < 2; ++t)
#pragma unroll
    for (int n = 0; n < 8; ++n)
      acc[t][n] = (floatx4){0.f, 0.f, 0.f, 0.f};

#pragma unroll
  for (int ks = 0; ks < 4; ++ks) {
    bf16x8 a[2];
#pragma unroll
    for (int t = 0; t < 2; ++t) {
      int r = row0 + t * 16 + lrow;
      uint4 tmp = {0u, 0u, 0u, 0u};
      if (r < M) {
        if (A32) {
          float4 f0 = *(const float4*)(A32 + (size_t)r * HH + ks * 32 + lk);
          float4 f1 = *(const float4*)(A32 + (size_t)r * HH + ks * 32 + lk + 4);
          tmp.x = f2b(f0.x) | (f2b(f0.y) << 16);
          tmp.y = f2b(f0.z) | (f2b(f0.w) << 16);
          tmp.z = f2b(f1.x) | (f2b(f1.y) << 16);
          tmp.w = f2b(f1.z) | (f2b(f1.w) << 16);
        } else {
          tmp = *(const uint4*)(A16 + (size_t)r * HH + ks * 32 + lk);
        }
      }
      a[t] = __builtin_bit_cast(bf16x8, tmp);
    }
#pragma unroll
    for (int n = 0; n < 8; ++n) {
      bf16x8 b = __builtin_bit_cast(bf16x8, *(const uint4*)&Wt[n * 16 + lrow][ks * 32 + lk]);
      acc[0][n] = __builtin_amdgcn_mfma_f32_16x16x32_bf16(a[0], b, acc[0][n], 0, 0, 0);
      acc[1][n] = __builtin_amdgcn_mfma_f32_16x16x32_bf16(a[1], b, acc[1][n], 0, 0, 0);
    }
  }

  float bc[8];
#pragma unroll
  for (int n = 0; n < 8; ++n) bc[n] = bias[n * 16 + lrow];

  __syncthreads();   // Wt dead; reuse as per-wave 16x136 transpose buffers
  uint16_t* tbuf = ((uint16_t*)Wt) + wave * (16 * 136);
  const int rbase = (lane >> 4) * 4;
  const int trow = lane >> 2;          // 0..15 readback row
  const int tseg = (lane & 3) * 32;    // 32-col segment

#pragma unroll
  for (int t = 0; t < 2; ++t) {
    // scatter: scalar LDS writes (2-way bank alias = free)
#pragma unroll
    for (int r = 0; r < 4; ++r) {
      int grow = row0 + t * 16 + rbase + r;
      float sc = (scale && grow < M) ? scale[grow] : 1.0f;
#pragma unroll
      for (int n = 0; n < 8; ++n) {
        float v = acc[t][n][r] + bc[n];
        if (do_relu) v = fmaxf(v, 0.f);
        v *= sc;
        tbuf[(rbase + r) * 136 + n * 16 + lrow] = (uint16_t)f2b(v);
      }
    }
    __syncthreads();
    // gather: row-contiguous uint4 reads + 16B global stores
    int grow = row0 + t * 16 + trow;
    if (grow < M) {
#pragma unroll
      for (int j = 0; j < 4; ++j) {
        uint4 v = *(const uint4*)&tbuf[trow * 136 + tseg + j * 8];
        *(uint4*)(Out + (size_t)grow * HH + tseg + j * 8) = v;
      }
    }
    __syncthreads();
  }
}

// ================= aggregation: pre-scaled rows, pure gather-sum, unroll-4 =================
__global__ __launch_bounds__(256) void k_agg(
    const uint16_t* __restrict__ hw2, const int* __restrict__ off,
    const int* __restrict__ csrs, const float* __restrict__ inv,
    const int* __restrict__ order,
    uint16_t* __restrict__ hout, int do_relu)
{
  int slot = blockIdx.x * 16 + (threadIdx.x >> 4);
  if (slot >= NN) return;
  int node = order[slot];
  int c = (threadIdx.x & 15) * 8;   // 8 channels = 16 B per lane

  uint4 sv = *(const uint4*)(hw2 + (size_t)node * HH + c);
  float a[8] = {0.f, 0.f, 0.f, 0.f, 0.f, 0.f, 0.f, 0.f};
  addrow(a, sv);                    // self term (already inv[node]-scaled)

  int e0 = off[node], e1 = off[node + 1];
  int e = e0;
  for (; e + 4 <= e1; e += 4) {
    int s0 = csrs[e + 0], s1 = csrs[e + 1], s2 = csrs[e + 2], s3 = csrs[e + 3];
    uint4 v0 = *(const uint4*)(hw2 + (size_t)s0 * HH + c);
    uint4 v1 = *(const uint4*)(hw2 + (size_t)s1 * HH + c);
    uint4 v2 = *(const uint4*)(hw2 + (size_t)s2 * HH + c);
    uint4 v3 = *(const uint4*)(hw2 + (size_t)s3 * HH + c);
    addrow(a, v0); addrow(a, v1); addrow(a, v2); addrow(a, v3);
  }
  for (; e < e1; ++e) {
    int s = csrs[e];
    uint4 v = *(const uint4*)(hw2 + (size_t)s * HH + c);
    addrow(a, v);
  }
  float invd = inv[node];
#pragma unroll
  for (int j = 0; j < 8; ++j) {
    a[j] *= invd;
    if (do_relu) a[j] = fmaxf(a[j], 0.f);
  }
  uint4 o;
  o.x = f2b(a[0]) | (f2b(a[1]) << 16);
  o.y = f2b(a[2]) | (f2b(a[3]) << 16);
  o.z = f2b(a[4]) | (f2b(a[5]) << 16);
  o.w = f2b(a[6]) | (f2b(a[7]) << 16);
  *(uint4*)(hout + (size_t)node * HH + c) = o;
}

// ================= fused pool + decoder: one block per graph, zero atomics =================
__global__ __launch_bounds__(256) void k_pooldec(
    const uint16_t* __restrict__ h, const int* __restrict__ gstart,
    const float* __restrict__ w1, const float* __restrict__ b1,
    const float* __restrict__ w2, const float* __restrict__ b2,
    float* __restrict__ out)
{
  __shared__ float red[16][132];   // +4 pad
  __shared__ float p[128], tmpv[128];
  int g = blockIdx.x;
  int tid = threadIdx.x;
  int slot = tid >> 4;
  int c = (tid & 15) * 8;

  int r0 = gstart[g], r1 = gstart[g + 1];
  float a[8] = {0.f, 0.f, 0.f, 0.f, 0.f, 0.f, 0.f, 0.f};
  for (int r = r0 + slot; r < r1; r += 16) {
    uint4 v = *(const uint4*)(h + (size_t)r * HH + c);
    a[0] += b2f(v.x & 0xFFFFu); a[1] += b2f(v.x >> 16);
    a[2] += b2f(v.y & 0xFFFFu); a[3] += b2f(v.y >> 16);
    a[4] += b2f(v.z & 0xFFFFu); a[5] += b2f(v.z >> 16);
    a[6] += b2f(v.w & 0xFFFFu); a[7] += b2f(v.w >> 16);
  }
  *(float4*)&red[slot][c]     = make_float4(a[0], a[1], a[2], a[3]);
  *(float4*)&red[slot][c + 4] = make_float4(a[4], a[5], a[6], a[7]);
  __syncthreads();
  if (tid < 128) {
    float s = 0.f;
#pragma unroll
    for (int k = 0; k < 16; ++k) s += red[k][tid];
    p[tid] = s;
  }
  __syncthreads();
  if (tid < 128) {
    float acc1 = b1[tid];
    for (int k = 0; k < 128; ++k) acc1 += p[k] * w1[k * 128 + tid];
    tmpv[tid] = fmaxf(acc1, 0.f);
  }
  __syncthreads();
  if (tid < 10) {
    float o = b2[tid];
    for (int k = 0; k < 128; ++k) o += tmpv[k] * w2[k * 10 + tid];
    out[g * 10 + tid] = o;
  }
}

extern "C" void kernel_launch(void* const* d_in, const int* in_sizes, int n_in,
                              void* d_out, int out_size, void* d_ws, size_t ws_size,
                              hipStream_t stream) {
  const float* x       = (const float*)d_in[0];
  const int*   eidx    = (const int*)d_in[1];
  const int*   src     = eidx;            // edge_index[0]
  const int*   dst     = eidx + NE;       // edge_index[1]
  const int*   batch   = (const int*)d_in[3];
  const float* enc_w1  = (const float*)d_in[4];
  const float* enc_b1  = (const float*)d_in[5];
  const float* enc_w2  = (const float*)d_in[6];
  const float* enc_b2  = (const float*)d_in[7];
  const float* conv_w  = (const float*)d_in[8];
  const float* conv_b  = (const float*)d_in[9];
  const float* dec_w1  = (const float*)d_in[10];
  const float* dec_b1  = (const float*)d_in[11];
  const float* dec_w2  = (const float*)d_in[12];
  const float* dec_b2  = (const float*)d_in[13];
  float* out = (float*)d_out;

  char* ws = (char*)d_ws;
  size_t o = 0;
  auto alloc = [&](size_t bytes) -> char* {
    char* p = ws + o;
    o += (bytes + 255) & ~(size_t)255;
    return p;
  };
  int*      off     = (int*)alloc((size_t)(NN + 1) * 4);
  int*      csrs    = (int*)alloc((size_t)NE * 4);
  float*    inv     = (float*)alloc((size_t)NN * 4);
  int*      blkcntA = (int*)alloc((size_t)NBLK * NB * 4);
  int*      poffA   = (int*)alloc((size_t)NBLK * NB * 4);
  int*      blkcntB = (int*)alloc((size_t)NBLK * NB * 4);
  int*      poffB   = (int*)alloc((size_t)NBLK * NB * 4);
  int*      colsumA = (int*)alloc((size_t)NB * 4);
  int*      colsumB = (int*)alloc((size_t)NB * 4);
  int*      gbaseA  = (int*)alloc((size_t)(NB + 1) * 4);
  int*      gbaseB  = (int*)alloc((size_t)(NB + 1) * 4);
  int*      dhist2  = (int*)alloc((size_t)NB * 64 * 4);
  int*      dcur    = (int*)alloc(64 * 4);
  int*      order   = (int*)alloc((size_t)NN * 4);
  int*      gstart  = (int*)alloc((size_t)(NG + 1) * 4);
  uint16_t* buf0    = (uint16_t*)alloc((size_t)NN * HH * 2);
  uint16_t* buf1    = (uint16_t*)alloc((size_t)NN * HH * 2);
  uint2*    pairsA  = (uint2*)buf1;                          // 12.8 MB, dead before encoder
  uint32_t* pairB   = (uint32_t*)((char*)buf1 + (size_t)NE * 8);  // +6.4 MB, still < 25.6 MB

  // CSR build: sort by src-bucket, then stable by dst-bucket, then per-bucket by dst node
  k_cntA<<<dim3(NBLK), dim3(256), 0, stream>>>(src, blkcntA);
  k_colscan<<<dim3(NB), dim3(64), 0, stream>>>(blkcntA, poffA, colsumA);
  k_gscan<<<dim3(1), dim3(256), 0, stream>>>(colsumA, gbaseA, off, 0);
  k_placeA<<<dim3(NBLK), dim3(256), 0, stream>>>(src, dst, poffA, gbaseA, pairsA);
  k_cntB<<<dim3(NBLK), dim3(256), 0, stream>>>(pairsA, blkcntB);
  k_colscan<<<dim3(NB), dim3(64), 0, stream>>>(blkcntB, poffB, colsumB);
  k_gscan<<<dim3(1), dim3(256), 0, stream>>>(colsumB, gbaseB, off, 1);
  k_placeB<<<dim3(NBLK), dim3(256), 0, stream>>>(pairsA, poffB, gbaseB, pairB);
  k_bucket_sort<<<dim3(NB), dim3(256), 0, stream>>>(pairB, gbaseB, batch, off, inv, csrs,
                                                    dhist2, gstart);

  // degree-LPT order
  const int NBK = (NN + 255) / 256;
  k_dscan<<<dim3(1), dim3(64), 0, stream>>>(dhist2, dcur);
  k_dplace<<<dim3(NBK), dim3(256), 0, stream>>>(off, dcur, order);

  // encoder (first GEMM reads fp32 x directly)
  const int GB = (NN + 127) / 128;   // 782
  k_gemm<<<dim3(GB), dim3(256), 0, stream>>>(nullptr, x, enc_w1, enc_b1, nullptr, buf1, NN, 1);
  k_gemm<<<dim3(GB), dim3(256), 0, stream>>>(buf1, nullptr, enc_w2, enc_b2, nullptr, buf0, NN, 0);

  // 3 GCN layers: conv GEMM writes inv[r]-pre-scaled rows; agg is pure gather-sum
  const int AB = (NN + 15) / 16;   // 6250
  k_gemm<<<dim3(GB), dim3(256), 0, stream>>>(buf0, nullptr, conv_w + 0 * 16384, conv_b + 0,   inv, buf1, NN, 0);
  k_agg <<<dim3(AB), dim3(256), 0, stream>>>(buf1, off, csrs, inv, order, buf0, 1);
  k_gemm<<<dim3(GB), dim3(256), 0, stream>>>(buf0, nullptr, conv_w + 1 * 16384, conv_b + 128, inv, buf1, NN, 0);
  k_agg <<<dim3(AB), dim3(256), 0, stream>>>(buf1, off, csrs, inv, order, buf0, 1);
  k_gemm<<<dim3(GB), dim3(256), 0, stream>>>(buf0, nullptr, conv_w + 2 * 16384, conv_b + 256, inv, buf1, NN, 0);
  k_agg <<<dim3(AB), dim3(256), 0, stream>>>(buf1, off, csrs, inv, order, buf0, 0);

  // fused pool + decoder
  k_pooldec<<<dim3(NG), dim3(256), 0, stream>>>(buf0, gstart, dec_w1, dec_b1, dec_w2, dec_b2, out);
}

// Round 12
// 527.288 us; speedup vs baseline: 1.3704x; 1.0328x over previous
//
#include <hip/hip_runtime.h>
#include <hip/hip_bf16.h>
#include <cstdint>
#include <cstddef>

#define NN 100000      // nodes
#define NE 1600000     // edges
#define HH 128         // hidden dim
#define NG 256         // graphs

#define NB 196         // buckets (512 nodes each; 196*512 = 100352 >= NN)
#define BSH 9          // bucket shift
#define BMSK 511
#define CHUNK 16384    // edges per binning block
#define NBLK 98        // ceil(NE / CHUNK)

typedef __bf16 bf16x8 __attribute__((ext_vector_type(8)));
typedef float floatx4 __attribute__((ext_vector_type(4)));

__device__ __forceinline__ uint32_t f2b(float f) {
  union { float f; uint32_t u; } v; v.f = f;
  uint32_t u = v.u;
  return (u + 0x7FFFu + ((u >> 16) & 1u)) >> 16;   // RNE to bf16 (raw 16 bits)
}
__device__ __forceinline__ float b2f(uint32_t h) {
  union { uint32_t u; float f; } v; v.u = h << 16;
  return v.f;
}
__device__ __forceinline__ void addrow(float* a, uint4 v) {
  a[0] += b2f(v.x & 0xFFFFu); a[1] += b2f(v.x >> 16);
  a[2] += b2f(v.y & 0xFFFFu); a[3] += b2f(v.y >> 16);
  a[4] += b2f(v.z & 0xFFFFu); a[5] += b2f(v.z >> 16);
  a[6] += b2f(v.w & 0xFFFFu); a[7] += b2f(v.w >> 16);
}

// ================= CSR build: src-bucket sort, then dst-bucket counting sort =================

__global__ __launch_bounds__(256) void k_cntA(const int* __restrict__ src,
                                              int* __restrict__ blkcnt) {
  __shared__ int h[NB];
  int t = threadIdx.x;
  if (t < NB) h[t] = 0;
  __syncthreads();
  int base = blockIdx.x * CHUNK, end = min(base + CHUNK, NE);
  for (int i = base + t; i < end; i += 256) atomicAdd(&h[src[i] >> BSH], 1);
  __syncthreads();
  if (t < NB) blkcnt[blockIdx.x * NB + t] = h[t];
}

__global__ __launch_bounds__(256) void k_cntB(const uint2* __restrict__ pairs,
                                              int* __restrict__ blkcnt) {
  __shared__ int h[NB];
  int t = threadIdx.x;
  if (t < NB) h[t] = 0;
  __syncthreads();
  int base = blockIdx.x * CHUNK, end = min(base + CHUNK, NE);
  for (int i = base + t; i < end; i += 256) atomicAdd(&h[pairs[i].y >> BSH], 1);
  __syncthreads();
  if (t < NB) blkcnt[blockIdx.x * NB + t] = h[t];
}

__global__ __launch_bounds__(64) void k_colscan(const int* __restrict__ blkcnt,
                                                int* __restrict__ poff,
                                                int* __restrict__ colsum) {
  int b = blockIdx.x, t = threadIdx.x;
  int carry = 0;
  for (int base = 0; base < NBLK; base += 64) {
    int r = base + t;
    int x = (r < NBLK) ? blkcnt[r * NB + b] : 0;
    int v = x;
    for (int d = 1; d < 64; d <<= 1) { int u = __shfl_up(v, d); if (t >= d) v += u; }
    if (r < NBLK) poff[r * NB + b] = carry + v - x;
    carry += __shfl(v, 63);
  }
  if (t == 0) colsum[b] = carry;
}

__global__ void k_gscan(const int* __restrict__ colsum, int* __restrict__ gbase,
                        int* __restrict__ off, int set_off) {
  __shared__ int s[256];
  int t = threadIdx.x;
  int x = (t < NB) ? colsum[t] : 0;
  s[t] = x; __syncthreads();
  for (int d = 1; d < 256; d <<= 1) {
    int v = (t >= d) ? s[t - d] : 0;
    __syncthreads();
    s[t] += v;
    __syncthreads();
  }
  if (t < NB) gbase[t] = s[t] - x;
  if (t == 0) { gbase[NB] = NE; if (set_off) off[NN] = NE; }
}

__global__ __launch_bounds__(256) void k_placeA(const int* __restrict__ src,
                                                const int* __restrict__ dst,
                                                const int* __restrict__ poff,
                                                const int* __restrict__ gbase,
                                                uint2* __restrict__ pairs) {
  __shared__ int cur[NB];
  int t = threadIdx.x;
  if (t < NB) cur[t] = poff[blockIdx.x * NB + t] + gbase[t];
  __syncthreads();
  int base = blockIdx.x * CHUNK, end = min(base + CHUNK, NE);
  for (int i = base + t; i < end; i += 256) {
    int s = src[i], d = dst[i];
    int p = atomicAdd(&cur[s >> BSH], 1);
    pairs[p] = make_uint2((unsigned)s, (unsigned)d);
  }
}

__global__ __launch_bounds__(256) void k_placeB(const uint2* __restrict__ pairs,
                                                const int* __restrict__ poff,
                                                const int* __restrict__ gbase,
                                                uint32_t* __restrict__ outb) {
  __shared__ int cur[NB];
  int t = threadIdx.x;
  if (t < NB) cur[t] = poff[blockIdx.x * NB + t] + gbase[t];
  __syncthreads();
  int base = blockIdx.x * CHUNK, end = min(base + CHUNK, NE);
  for (int i = base + t; i < end; i += 256) {
    uint2 v = pairs[i];
    int p = atomicAdd(&cur[v.y >> BSH], 1);
    outb[p] = v.x | ((v.y & (unsigned)BMSK) << 17);
  }
}

// per-dst-bucket counting sort -> off/inv/csrs; fused per-block degree hist + gstart
__global__ __launch_bounds__(256) void k_bucket_sort(
    const uint32_t* __restrict__ pairbuf, const int* __restrict__ gbase,
    const int* __restrict__ batch,
    int* __restrict__ off, float* __restrict__ inv, int* __restrict__ csrs,
    int* __restrict__ dhist2, int* __restrict__ gstart)
{
  __shared__ int cnt[512];
  __shared__ int loff[512];
  __shared__ int psum[256];
  int b = blockIdx.x;
  int tid = threadIdx.x;
  cnt[tid] = 0; cnt[tid + 256] = 0;
  __syncthreads();
  int s0 = gbase[b], s1 = gbase[b + 1];
  for (int i = s0 + tid; i < s1; i += 256)
    atomicAdd(&cnt[pairbuf[i] >> 17], 1);
  __syncthreads();
  int a0 = cnt[2 * tid], a1 = cnt[2 * tid + 1];
  int s = a0 + a1;
  psum[tid] = s;
  __syncthreads();
  for (int d = 1; d < 256; d <<= 1) {
    int v = (tid >= d) ? psum[tid - d] : 0;
    __syncthreads();
    psum[tid] += v;
    __syncthreads();
  }
  int excl = psum[tid] - s;
  loff[2 * tid] = excl;
  loff[2 * tid + 1] = excl + a0;
  __syncthreads();
  int* h64 = psum;               // psum dead after excl computed
  if (tid < 64) h64[tid] = 0;
  __syncthreads();
#pragma unroll
  for (int k = 0; k < 2; ++k) {
    int i = tid + k * 256;
    int node = b * 512 + i;
    if (node < NN) {
      off[node] = s0 + loff[i];
      inv[node] = rsqrtf((float)cnt[i] + 1.0f);
      int d = cnt[i]; if (d > 63) d = 63;
      atomicAdd(&h64[d], 1);
    }
  }
  // gstart for this block's node range (batch sorted)
  {
    int n0 = b * 512, n1 = min(n0 + 512, NN);
    for (int i = n0 + tid; i < n1; i += 256) {
      int bb = batch[i];
      if (i == 0) { for (int g = 0; g <= bb; ++g) gstart[g] = 0; }
      else { int aa = batch[i - 1]; for (int g = aa + 1; g <= bb; ++g) gstart[g] = i; }
      if (i == NN - 1) { for (int g = bb + 1; g <= NG; ++g) gstart[g] = NN; }
    }
  }
  __syncthreads();
  if (tid < 64) dhist2[b * 64 + tid] = h64[tid];
  cnt[tid] = loff[tid]; cnt[tid + 256] = loff[tid + 256];   // counters -> cursors
  __syncthreads();
  for (int i = s0 + tid; i < s1; i += 256) {
    uint32_t v = pairbuf[i];
    int p = atomicAdd(&cnt[v >> 17], 1);
    csrs[s0 + p] = (int)(v & 0x1FFFFu);
  }
}

// ================= degree order: column-sum of dhist2 + descending scan (LPT) =================
__global__ void k_dscan(const int* __restrict__ dhist2, int* __restrict__ dcur) {
  int t = threadIdx.x;             // 64 threads
  int sum = 0;
  for (int r = 0; r < NB; ++r) sum += dhist2[r * 64 + (63 - t)];
  int v = sum;
  for (int d = 1; d < 64; d <<= 1) { int u = __shfl_up(v, d); if (t >= d) v += u; }
  dcur[63 - t] = v - sum;
}

__global__ __launch_bounds__(256) void k_dplace(const int* __restrict__ off,
                                                int* __restrict__ dcur,
                                                int* __restrict__ order) {
  __shared__ int h[64], base[64];
  int t = threadIdx.x;
  if (t < 64) h[t] = 0;
  __syncthreads();
  int i = blockIdx.x * 256 + t;
  int d = 0, ld = 0;
  if (i < NN) { d = off[i + 1] - off[i]; if (d > 63) d = 63; ld = atomicAdd(&h[d], 1); }
  __syncthreads();
  if (t < 64) base[t] = h[t] ? atomicAdd(&dcur[t], h[t]) : 0;
  __syncthreads();
  if (i < NN) order[base[d] + ld] = i;
}

// ================= GEMM: Out[M,128] = bf16( scale[r] * (relu?(A@W + bias)) ) =================
// Operand-swapped MFMA: acc holds C^T tile -> each lane owns 4 consecutive output
// cols of one row -> packed uint2 stores (16/thread vs 64 scalar). Loads unchanged.
__global__ __launch_bounds__(256) void k_gemm(
    const uint16_t* __restrict__ A16, const float* __restrict__ A32,
    const float* __restrict__ W, const float* __restrict__ bias,
    const float* __restrict__ scale,      // nullptr or per-row scale (inv)
    uint16_t* __restrict__ Out, int M, int do_relu)
{
  __shared__ uint16_t Wt[128][136];
  const int tid = threadIdx.x;

  for (int it = 0; it < 16; ++it) {
    int idx = tid + it * 256;
    int n = idx & 127;
    int k0 = (idx >> 7) * 4;
    uint2 wv;
    wv.x = f2b(W[(k0 + 0) * 128 + n]) | (f2b(W[(k0 + 1) * 128 + n]) << 16);
    wv.y = f2b(W[(k0 + 2) * 128 + n]) | (f2b(W[(k0 + 3) * 128 + n]) << 16);
    *(uint2*)&Wt[n][k0] = wv;
  }
  __syncthreads();

  const int lane = tid & 63;
  const int wave = tid >> 6;
  const int lrow = lane & 15;
  const int quad = lane >> 4;
  const int lk = quad * 8;
  const int row0 = blockIdx.x * 128 + wave * 32;

  floatx4 acc[2][8];
#pragma unroll
  for (int t = 0; t < 2; ++t)
#pragma unroll
    for (int n = 0; n < 8; ++n)
      acc[t][n] = (floatx4){0.f, 0.f, 0.f, 0.f};

#pragma unroll
  for (int ks = 0; ks < 4; ++ks) {
    bf16x8 a[2];
#pragma unroll
    for (int t = 0; t < 2; ++t) {
      int r = row0 + t * 16 + lrow;
      uint4 tmp = {0u, 0u, 0u, 0u};
      if (r < M) {
        if (A32) {
          float4 f0 = *(const float4*)(A32 + (size_t)r * HH + ks * 32 + lk);
          float4 f1 = *(const float4*)(A32 + (size_t)r * HH + ks * 32 + lk + 4);
          tmp.x = f2b(f0.x) | (f2b(f0.y) << 16);
          tmp.y = f2b(f0.z) | (f2b(f0.w) << 16);
          tmp.z = f2b(f1.x) | (f2b(f1.y) << 16);
          tmp.w = f2b(f1.z) | (f2b(f1.w) << 16);
        } else {
          tmp = *(const uint4*)(A16 + (size_t)r * HH + ks * 32 + lk);
        }
      }
      a[t] = __builtin_bit_cast(bf16x8, tmp);
    }
#pragma unroll
    for (int n = 0; n < 8; ++n) {
      bf16x8 b = __builtin_bit_cast(bf16x8, *(const uint4*)&Wt[n * 16 + lrow][ks * 32 + lk]);
      // swapped operands: acc = W_frag * A_frag -> C^T lane layout
      acc[0][n] = __builtin_amdgcn_mfma_f32_16x16x32_bf16(b, a[0], acc[0][n], 0, 0, 0);
      acc[1][n] = __builtin_amdgcn_mfma_f32_16x16x32_bf16(b, a[1], acc[1][n], 0, 0, 0);
    }
  }

  // bias per output col: col = n*16 + quad*4 + r  -> float4 component r
  float4 b4[8];
#pragma unroll
  for (int n = 0; n < 8; ++n) b4[n] = *(const float4*)(bias + n * 16 + quad * 4);

#pragma unroll
  for (int t = 0; t < 2; ++t) {
    int row = row0 + t * 16 + lrow;
    if (row < M) {
      float sc = scale ? scale[row] : 1.0f;
      uint16_t* orow = Out + (size_t)row * HH;
#pragma unroll
      for (int n = 0; n < 8; ++n) {
        float v0 = acc[t][n][0] + b4[n].x;
        float v1 = acc[t][n][1] + b4[n].y;
        float v2 = acc[t][n][2] + b4[n].z;
        float v3 = acc[t][n][3] + b4[n].w;
        if (do_relu) {
          v0 = fmaxf(v0, 0.f); v1 = fmaxf(v1, 0.f);
          v2 = fmaxf(v2, 0.f); v3 = fmaxf(v3, 0.f);
        }
        v0 *= sc; v1 *= sc; v2 *= sc; v3 *= sc;
        uint2 o;
        o.x = f2b(v0) | (f2b(v1) << 16);
        o.y = f2b(v2) | (f2b(v3) << 16);
        *(uint2*)(orow + n * 16 + quad * 4) = o;
      }
    }
  }
}

// ================= aggregation: pre-scaled rows, pure gather-sum, unroll-4 =================
__global__ __launch_bounds__(256) void k_agg(
    const uint16_t* __restrict__ hw2, const int* __restrict__ off,
    const int* __restrict__ csrs, const float* __restrict__ inv,
    const int* __restrict__ order,
    uint16_t* __restrict__ hout, int do_relu)
{
  int slot = blockIdx.x * 16 + (threadIdx.x >> 4);
  if (slot >= NN) return;
  int node = order[slot];
  int c = (threadIdx.x & 15) * 8;   // 8 channels = 16 B per lane

  uint4 sv = *(const uint4*)(hw2 + (size_t)node * HH + c);
  float a[8] = {0.f, 0.f, 0.f, 0.f, 0.f, 0.f, 0.f, 0.f};
  addrow(a, sv);                    // self term (already inv[node]-scaled)

  int e0 = off[node], e1 = off[node + 1];
  int e = e0;
  for (; e + 4 <= e1; e += 4) {
    int s0 = csrs[e + 0], s1 = csrs[e + 1], s2 = csrs[e + 2], s3 = csrs[e + 3];
    uint4 v0 = *(const uint4*)(hw2 + (size_t)s0 * HH + c);
    uint4 v1 = *(const uint4*)(hw2 + (size_t)s1 * HH + c);
    uint4 v2 = *(const uint4*)(hw2 + (size_t)s2 * HH + c);
    uint4 v3 = *(const uint4*)(hw2 + (size_t)s3 * HH + c);
    addrow(a, v0); addrow(a, v1); addrow(a, v2); addrow(a, v3);
  }
  for (; e < e1; ++e) {
    int s = csrs[e];
    uint4 v = *(const uint4*)(hw2 + (size_t)s * HH + c);
    addrow(a, v);
  }
  float invd = inv[node];
#pragma unroll
  for (int j = 0; j < 8; ++j) {
    a[j] *= invd;
    if (do_relu) a[j] = fmaxf(a[j], 0.f);
  }
  uint4 o;
  o.x = f2b(a[0]) | (f2b(a[1]) << 16);
  o.y = f2b(a[2]) | (f2b(a[3]) << 16);
  o.z = f2b(a[4]) | (f2b(a[5]) << 16);
  o.w = f2b(a[6]) | (f2b(a[7]) << 16);
  *(uint4*)(hout + (size_t)node * HH + c) = o;
}

// ================= fused pool + decoder: one block per graph, zero atomics =================
__global__ __launch_bounds__(256) void k_pooldec(
    const uint16_t* __restrict__ h, const int* __restrict__ gstart,
    const float* __restrict__ w1, const float* __restrict__ b1,
    const float* __restrict__ w2, const float* __restrict__ b2,
    float* __restrict__ out)
{
  __shared__ float red[16][132];   // +4 pad
  __shared__ float p[128], tmpv[128];
  int g = blockIdx.x;
  int tid = threadIdx.x;
  int slot = tid >> 4;
  int c = (tid & 15) * 8;

  int r0 = gstart[g], r1 = gstart[g + 1];
  float a[8] = {0.f, 0.f, 0.f, 0.f, 0.f, 0.f, 0.f, 0.f};
  for (int r = r0 + slot; r < r1; r += 16) {
    uint4 v = *(const uint4*)(h + (size_t)r * HH + c);
    a[0] += b2f(v.x & 0xFFFFu); a[1] += b2f(v.x >> 16);
    a[2] += b2f(v.y & 0xFFFFu); a[3] += b2f(v.y >> 16);
    a[4] += b2f(v.z & 0xFFFFu); a[5] += b2f(v.z >> 16);
    a[6] += b2f(v.w & 0xFFFFu); a[7] += b2f(v.w >> 16);
  }
  *(float4*)&red[slot][c]     = make_float4(a[0], a[1], a[2], a[3]);
  *(float4*)&red[slot][c + 4] = make_float4(a[4], a[5], a[6], a[7]);
  __syncthreads();
  if (tid < 128) {
    float s = 0.f;
#pragma unroll
    for (int k = 0; k < 16; ++k) s += red[k][tid];
    p[tid] = s;
  }
  __syncthreads();
  if (tid < 128) {
    float acc1 = b1[tid];
    for (int k = 0; k < 128; ++k) acc1 += p[k] * w1[k * 128 + tid];
    tmpv[tid] = fmaxf(acc1, 0.f);
  }
  __syncthreads();
  if (tid < 10) {
    float o = b2[tid];
    for (int k = 0; k < 128; ++k) o += tmpv[k] * w2[k * 10 + tid];
    out[g * 10 + tid] = o;
  }
}

extern "C" void kernel_launch(void* const* d_in, const int* in_sizes, int n_in,
                              void* d_out, int out_size, void* d_ws, size_t ws_size,
                              hipStream_t stream) {
  const float* x       = (const float*)d_in[0];
  const int*   eidx    = (const int*)d_in[1];
  const int*   src     = eidx;            // edge_index[0]
  const int*   dst     = eidx + NE;       // edge_index[1]
  const int*   batch   = (const int*)d_in[3];
  const float* enc_w1  = (const float*)d_in[4];
  const float* enc_b1  = (const float*)d_in[5];
  const float* enc_w2  = (const float*)d_in[6];
  const float* enc_b2  = (const float*)d_in[7];
  const float* conv_w  = (const float*)d_in[8];
  const float* conv_b  = (const float*)d_in[9];
  const float* dec_w1  = (const float*)d_in[10];
  const float* dec_b1  = (const float*)d_in[11];
  const float* dec_w2  = (const float*)d_in[12];
  const float* dec_b2  = (const float*)d_in[13];
  float* out = (float*)d_out;

  char* ws = (char*)d_ws;
  size_t o = 0;
  auto alloc = [&](size_t bytes) -> char* {
    char* p = ws + o;
    o += (bytes + 255) & ~(size_t)255;
    return p;
  };
  int*      off     = (int*)alloc((size_t)(NN + 1) * 4);
  int*      csrs    = (int*)alloc((size_t)NE * 4);
  float*    inv     = (float*)alloc((size_t)NN * 4);
  int*      blkcntA = (int*)alloc((size_t)NBLK * NB * 4);
  int*      poffA   = (int*)alloc((size_t)NBLK * NB * 4);
  int*      blkcntB = (int*)alloc((size_t)NBLK * NB * 4);
  int*      poffB   = (int*)alloc((size_t)NBLK * NB * 4);
  int*      colsumA = (int*)alloc((size_t)NB * 4);
  int*      colsumB = (int*)alloc((size_t)NB * 4);
  int*      gbaseA  = (int*)alloc((size_t)(NB + 1) * 4);
  int*      gbaseB  = (int*)alloc((size_t)(NB + 1) * 4);
  int*      dhist2  = (int*)alloc((size_t)NB * 64 * 4);
  int*      dcur    = (int*)alloc(64 * 4);
  int*      order   = (int*)alloc((size_t)NN * 4);
  int*      gstart  = (int*)alloc((size_t)(NG + 1) * 4);
  uint16_t* buf0    = (uint16_t*)alloc((size_t)NN * HH * 2);
  uint16_t* buf1    = (uint16_t*)alloc((size_t)NN * HH * 2);
  uint2*    pairsA  = (uint2*)buf1;                          // 12.8 MB, dead before encoder
  uint32_t* pairB   = (uint32_t*)((char*)buf1 + (size_t)NE * 8);  // +6.4 MB, still < 25.6 MB

  // CSR build: sort by src-bucket, then stable by dst-bucket, then per-bucket by dst node
  k_cntA<<<dim3(NBLK), dim3(256), 0, stream>>>(src, blkcntA);
  k_colscan<<<dim3(NB), dim3(64), 0, stream>>>(blkcntA, poffA, colsumA);
  k_gscan<<<dim3(1), dim3(256), 0, stream>>>(colsumA, gbaseA, off, 0);
  k_placeA<<<dim3(NBLK), dim3(256), 0, stream>>>(src, dst, poffA, gbaseA, pairsA);
  k_cntB<<<dim3(NBLK), dim3(256), 0, stream>>>(pairsA, blkcntB);
  k_colscan<<<dim3(NB), dim3(64), 0, stream>>>(blkcntB, poffB, colsumB);
  k_gscan<<<dim3(1), dim3(256), 0, stream>>>(colsumB, gbaseB, off, 1);
  k_placeB<<<dim3(NBLK), dim3(256), 0, stream>>>(pairsA, poffB, gbaseB, pairB);
  k_bucket_sort<<<dim3(NB), dim3(256), 0, stream>>>(pairB, gbaseB, batch, off, inv, csrs,
                                                    dhist2, gstart);

  // degree-LPT order
  const int NBK = (NN + 255) / 256;
  k_dscan<<<dim3(1), dim3(64), 0, stream>>>(dhist2, dcur);
  k_dplace<<<dim3(NBK), dim3(256), 0, stream>>>(off, dcur, order);

  // encoder (first GEMM reads fp32 x directly)
  const int GB = (NN + 127) / 128;   // 782
  k_gemm<<<dim3(GB), dim3(256), 0, stream>>>(nullptr, x, enc_w1, enc_b1, nullptr, buf1, NN, 1);
  k_gemm<<<dim3(GB), dim3(256), 0, stream>>>(buf1, nullptr, enc_w2, enc_b2, nullptr, buf0, NN, 0);

  // 3 GCN layers: conv GEMM writes inv[r]-pre-scaled rows; agg is pure gather-sum
  const int AB = (NN + 15) / 16;   // 6250
  k_gemm<<<dim3(GB), dim3(256), 0, stream>>>(buf0, nullptr, conv_w + 0 * 16384, conv_b + 0,   inv, buf1, NN, 0);
  k_agg <<<dim3(AB), dim3(256), 0, stream>>>(buf1, off, csrs, inv, order, buf0, 1);
  k_gemm<<<dim3(GB), dim3(256), 0, stream>>>(buf0, nullptr, conv_w + 1 * 16384, conv_b + 128, inv, buf1, NN, 0);
  k_agg <<<dim3(AB), dim3(256), 0, stream>>>(buf1, off, csrs, inv, order, buf0, 1);
  k_gemm<<<dim3(GB), dim3(256), 0, stream>>>(buf0, nullptr, conv_w + 2 * 16384, conv_b + 256, inv, buf1, NN, 0);
  k_agg <<<dim3(AB), dim3(256), 0, stream>>>(buf1, off, csrs, inv, order, buf0, 0);

  // fused pool + decoder
  k_pooldec<<<dim3(NG), dim3(256), 0, stream>>>(buf0, gstart, dec_w1, dec_b1, dec_w2, dec_b2, out);
}

// Round 13
// 518.713 us; speedup vs baseline: 1.3930x; 1.0165x over previous
//
#include <hip/hip_runtime.h>
#include <hip/hip_bf16.h>
#include <cstdint>
#include <cstddef>

#define NN 100000      // nodes
#define NE 1600000     // edges
#define HH 128         // hidden dim
#define NG 256         // graphs

#define NB 196         // buckets (512 nodes each; 196*512 = 100352 >= NN)
#define BSH 9          // bucket shift
#define BMSK 511
#define CHUNK 16384    // edges per binning block
#define NBLK 98        // ceil(NE / CHUNK)

typedef __bf16 bf16x8 __attribute__((ext_vector_type(8)));
typedef float floatx4 __attribute__((ext_vector_type(4)));

__device__ __forceinline__ uint32_t f2b(float f) {
  union { float f; uint32_t u; } v; v.f = f;
  uint32_t u = v.u;
  return (u + 0x7FFFu + ((u >> 16) & 1u)) >> 16;   // RNE to bf16 (raw 16 bits)
}
__device__ __forceinline__ float b2f(uint32_t h) {
  union { uint32_t u; float f; } v; v.u = h << 16;
  return v.f;
}
__device__ __forceinline__ void addrow(float* a, uint4 v) {
  a[0] += b2f(v.x & 0xFFFFu); a[1] += b2f(v.x >> 16);
  a[2] += b2f(v.y & 0xFFFFu); a[3] += b2f(v.y >> 16);
  a[4] += b2f(v.z & 0xFFFFu); a[5] += b2f(v.z >> 16);
  a[6] += b2f(v.w & 0xFFFFu); a[7] += b2f(v.w >> 16);
}

__device__ __forceinline__ void stage_w(uint16_t (*Wt)[136], const float* __restrict__ W,
                                        int tid) {
  for (int it = 0; it < 16; ++it) {
    int idx = tid + it * 256;
    int n = idx & 127;
    int k0 = (idx >> 7) * 4;
    uint2 wv;
    wv.x = f2b(W[(k0 + 0) * 128 + n]) | (f2b(W[(k0 + 1) * 128 + n]) << 16);
    wv.y = f2b(W[(k0 + 2) * 128 + n]) | (f2b(W[(k0 + 3) * 128 + n]) << 16);
    *(uint2*)&Wt[n][k0] = wv;
  }
}

// ================= CSR build: src-bucket sort, then dst-bucket counting sort =================

__global__ __launch_bounds__(256) void k_cntA(const int* __restrict__ src,
                                              int* __restrict__ blkcnt) {
  __shared__ int h[NB];
  int t = threadIdx.x;
  if (t < NB) h[t] = 0;
  __syncthreads();
  int base = blockIdx.x * CHUNK, end = min(base + CHUNK, NE);
  for (int i = base + t; i < end; i += 256) atomicAdd(&h[src[i] >> BSH], 1);
  __syncthreads();
  if (t < NB) blkcnt[blockIdx.x * NB + t] = h[t];
}

__global__ __launch_bounds__(256) void k_cntB(const uint2* __restrict__ pairs,
                                              int* __restrict__ blkcnt) {
  __shared__ int h[NB];
  int t = threadIdx.x;
  if (t < NB) h[t] = 0;
  __syncthreads();
  int base = blockIdx.x * CHUNK, end = min(base + CHUNK, NE);
  for (int i = base + t; i < end; i += 256) atomicAdd(&h[pairs[i].y >> BSH], 1);
  __syncthreads();
  if (t < NB) blkcnt[blockIdx.x * NB + t] = h[t];
}

// merged column-scan + global-scan (replaces k_colscan + k_gscan): 1 block
__global__ void k_scan(const int* __restrict__ blkcnt, int* __restrict__ poff,
                       int* __restrict__ gbase, int* __restrict__ off, int set_off) {
  __shared__ int s[256];
  int t = threadIdx.x;
  int tot = 0;
  if (t < NB) {
    for (int r = 0; r < NBLK; ++r) {
      poff[r * NB + t] = tot;          // column-local exclusive
      tot += blkcnt[r * NB + t];
    }
  }
  s[t] = (t < NB) ? tot : 0;
  __syncthreads();
  for (int d = 1; d < 256; d <<= 1) {
    int v = (t >= d) ? s[t - d] : 0;
    __syncthreads();
    s[t] += v;
    __syncthreads();
  }
  if (t < NB) gbase[t] = s[t] - tot;
  if (t == 0) { gbase[NB] = NE; if (set_off) off[NN] = NE; }
}

__global__ __launch_bounds__(256) void k_placeA(const int* __restrict__ src,
                                                const int* __restrict__ dst,
                                                const int* __restrict__ poff,
                                                const int* __restrict__ gbase,
                                                uint2* __restrict__ pairs) {
  __shared__ int cur[NB];
  int t = threadIdx.x;
  if (t < NB) cur[t] = poff[blockIdx.x * NB + t] + gbase[t];
  __syncthreads();
  int base = blockIdx.x * CHUNK, end = min(base + CHUNK, NE);
  for (int i = base + t; i < end; i += 256) {
    int s = src[i], d = dst[i];
    int p = atomicAdd(&cur[s >> BSH], 1);
    pairs[p] = make_uint2((unsigned)s, (unsigned)d);
  }
}

__global__ __launch_bounds__(256) void k_placeB(const uint2* __restrict__ pairs,
                                                const int* __restrict__ poff,
                                                const int* __restrict__ gbase,
                                                uint32_t* __restrict__ outb) {
  __shared__ int cur[NB];
  int t = threadIdx.x;
  if (t < NB) cur[t] = poff[blockIdx.x * NB + t] + gbase[t];
  __syncthreads();
  int base = blockIdx.x * CHUNK, end = min(base + CHUNK, NE);
  for (int i = base + t; i < end; i += 256) {
    uint2 v = pairs[i];
    int p = atomicAdd(&cur[v.y >> BSH], 1);
    outb[p] = v.x | ((v.y & (unsigned)BMSK) << 17);
  }
}

// per-dst-bucket counting sort -> off/inv/csrs; fused per-block degree hist + gstart
__global__ __launch_bounds__(256) void k_bucket_sort(
    const uint32_t* __restrict__ pairbuf, const int* __restrict__ gbase,
    const int* __restrict__ batch,
    int* __restrict__ off, float* __restrict__ inv, int* __restrict__ csrs,
    int* __restrict__ dhist2, int* __restrict__ gstart)
{
  __shared__ int cnt[512];
  __shared__ int loff[512];
  __shared__ int psum[256];
  int b = blockIdx.x;
  int tid = threadIdx.x;
  cnt[tid] = 0; cnt[tid + 256] = 0;
  __syncthreads();
  int s0 = gbase[b], s1 = gbase[b + 1];
  for (int i = s0 + tid; i < s1; i += 256)
    atomicAdd(&cnt[pairbuf[i] >> 17], 1);
  __syncthreads();
  int a0 = cnt[2 * tid], a1 = cnt[2 * tid + 1];
  int s = a0 + a1;
  psum[tid] = s;
  __syncthreads();
  for (int d = 1; d < 256; d <<= 1) {
    int v = (tid >= d) ? psum[tid - d] : 0;
    __syncthreads();
    psum[tid] += v;
    __syncthreads();
  }
  int excl = psum[tid] - s;
  loff[2 * tid] = excl;
  loff[2 * tid + 1] = excl + a0;
  __syncthreads();
  int* h64 = psum;               // psum dead after excl computed
  if (tid < 64) h64[tid] = 0;
  __syncthreads();
#pragma unroll
  for (int k = 0; k < 2; ++k) {
    int i = tid + k * 256;
    int node = b * 512 + i;
    if (node < NN) {
      off[node] = s0 + loff[i];
      inv[node] = rsqrtf((float)cnt[i] + 1.0f);
      int d = cnt[i]; if (d > 63) d = 63;
      atomicAdd(&h64[d], 1);
    }
  }
  // gstart for this block's node range (batch sorted)
  {
    int n0 = b * 512, n1 = min(n0 + 512, NN);
    for (int i = n0 + tid; i < n1; i += 256) {
      int bb = batch[i];
      if (i == 0) { for (int g = 0; g <= bb; ++g) gstart[g] = 0; }
      else { int aa = batch[i - 1]; for (int g = aa + 1; g <= bb; ++g) gstart[g] = i; }
      if (i == NN - 1) { for (int g = bb + 1; g <= NG; ++g) gstart[g] = NN; }
    }
  }
  __syncthreads();
  if (tid < 64) dhist2[b * 64 + tid] = h64[tid];
  cnt[tid] = loff[tid]; cnt[tid + 256] = loff[tid + 256];   // counters -> cursors
  __syncthreads();
  for (int i = s0 + tid; i < s1; i += 256) {
    uint32_t v = pairbuf[i];
    int p = atomicAdd(&cnt[v >> 17], 1);
    csrs[s0 + p] = (int)(v & 0x1FFFFu);
  }
}

// ================= degree order: column-sum of dhist2 + descending scan (LPT) =================
__global__ void k_dscan(const int* __restrict__ dhist2, int* __restrict__ dcur) {
  int t = threadIdx.x;             // 64 threads
  int sum = 0;
  for (int r = 0; r < NB; ++r) sum += dhist2[r * 64 + (63 - t)];
  int v = sum;
  for (int d = 1; d < 64; d <<= 1) { int u = __shfl_up(v, d); if (t >= d) v += u; }
  dcur[63 - t] = v - sum;
}

__global__ __launch_bounds__(256) void k_dplace(const int* __restrict__ off,
                                                int* __restrict__ dcur,
                                                int* __restrict__ order) {
  __shared__ int h[64], base[64];
  int t = threadIdx.x;
  if (t < 64) h[t] = 0;
  __syncthreads();
  int i = blockIdx.x * 256 + t;
  int d = 0, ld = 0;
  if (i < NN) { d = off[i + 1] - off[i]; if (d > 63) d = 63; ld = atomicAdd(&h[d], 1); }
  __syncthreads();
  if (t < 64) base[t] = h[t] ? atomicAdd(&dcur[t], h[t]) : 0;
  __syncthreads();
  if (i < NN) order[base[d] + ld] = i;
}

// ================= GEMM: Out[M,128] = bf16( scale[r] * (relu?(A@W + bias)) ) =================
// Operand-swapped MFMA: acc holds C^T tile -> packed uint2 stores.
__global__ __launch_bounds__(256) void k_gemm(
    const uint16_t* __restrict__ A16, const float* __restrict__ A32,
    const float* __restrict__ W, const float* __restrict__ bias,
    const float* __restrict__ scale,      // nullptr or per-row scale (inv)
    uint16_t* __restrict__ Out, int M, int do_relu)
{
  __shared__ uint16_t Wt[128][136];
  const int tid = threadIdx.x;
  stage_w(Wt, W, tid);
  __syncthreads();

  const int lane = tid & 63;
  const int wave = tid >> 6;
  const int lrow = lane & 15;
  const int quad = lane >> 4;
  const int lk = quad * 8;
  const int row0 = blockIdx.x * 128 + wave * 32;

  floatx4 acc[2][8];
#pragma unroll
  for (int t = 0; t < 2; ++t)
#pragma unroll
    for (int n = 0; n < 8; ++n)
      acc[t][n] = (floatx4){0.f, 0.f, 0.f, 0.f};

#pragma unroll
  for (int ks = 0; ks < 4; ++ks) {
    bf16x8 a[2];
#pragma unroll
    for (int t = 0; t < 2; ++t) {
      int r = row0 + t * 16 + lrow;
      uint4 tmp = {0u, 0u, 0u, 0u};
      if (r < M) {
        if (A32) {
          float4 f0 = *(const float4*)(A32 + (size_t)r * HH + ks * 32 + lk);
          float4 f1 = *(const float4*)(A32 + (size_t)r * HH + ks * 32 + lk + 4);
          tmp.x = f2b(f0.x) | (f2b(f0.y) << 16);
          tmp.y = f2b(f0.z) | (f2b(f0.w) << 16);
          tmp.z = f2b(f1.x) | (f2b(f1.y) << 16);
          tmp.w = f2b(f1.z) | (f2b(f1.w) << 16);
        } else {
          tmp = *(const uint4*)(A16 + (size_t)r * HH + ks * 32 + lk);
        }
      }
      a[t] = __builtin_bit_cast(bf16x8, tmp);
    }
#pragma unroll
    for (int n = 0; n < 8; ++n) {
      bf16x8 b = __builtin_bit_cast(bf16x8, *(const uint4*)&Wt[n * 16 + lrow][ks * 32 + lk]);
      acc[0][n] = __builtin_amdgcn_mfma_f32_16x16x32_bf16(b, a[0], acc[0][n], 0, 0, 0);
      acc[1][n] = __builtin_amdgcn_mfma_f32_16x16x32_bf16(b, a[1], acc[1][n], 0, 0, 0);
    }
  }

  float4 b4[8];
#pragma unroll
  for (int n = 0; n < 8; ++n) b4[n] = *(const float4*)(bias + n * 16 + quad * 4);

#pragma unroll
  for (int t = 0; t < 2; ++t) {
    int row = row0 + t * 16 + lrow;
    if (row < M) {
      float sc = scale ? scale[row] : 1.0f;
      uint16_t* orow = Out + (size_t)row * HH;
#pragma unroll
      for (int n = 0; n < 8; ++n) {
        float v0 = acc[t][n][0] + b4[n].x;
        float v1 = acc[t][n][1] + b4[n].y;
        float v2 = acc[t][n][2] + b4[n].z;
        float v3 = acc[t][n][3] + b4[n].w;
        if (do_relu) {
          v0 = fmaxf(v0, 0.f); v1 = fmaxf(v1, 0.f);
          v2 = fmaxf(v2, 0.f); v3 = fmaxf(v3, 0.f);
        }
        v0 *= sc; v1 *= sc; v2 *= sc; v3 *= sc;
        uint2 o;
        o.x = f2b(v0) | (f2b(v1) << 16);
        o.y = f2b(v2) | (f2b(v3) << 16);
        *(uint2*)(orow + n * 16 + quad * 4) = o;
      }
    }
  }
}

// ================= fused double GEMM: Out = scale * ((A@Wa+ba) @ Wb + bb) =================
// Phase-1 result lives in an LDS tile (bf16, same rounding as the old intermediate buffer).
__global__ __launch_bounds__(256) void k_gemm_dual(
    const uint16_t* __restrict__ A16,
    const float* __restrict__ Wa, const float* __restrict__ ba,
    const float* __restrict__ Wb, const float* __restrict__ bb,
    const float* __restrict__ scale,
    uint16_t* __restrict__ Out, int M)
{
  __shared__ uint16_t Wt[128][136];
  __shared__ uint16_t tile[128][136];
  const int tid = threadIdx.x;
  stage_w(Wt, Wa, tid);
  __syncthreads();

  const int lane = tid & 63;
  const int wave = tid >> 6;
  const int lrow = lane & 15;
  const int quad = lane >> 4;
  const int lk = quad * 8;
  const int row0 = blockIdx.x * 128 + wave * 32;
  const int trow0 = wave * 32;

  floatx4 acc[2][8];
#pragma unroll
  for (int t = 0; t < 2; ++t)
#pragma unroll
    for (int n = 0; n < 8; ++n)
      acc[t][n] = (floatx4){0.f, 0.f, 0.f, 0.f};

  // phase 1: global A -> C1 (swapped layout)
#pragma unroll
  for (int ks = 0; ks < 4; ++ks) {
    bf16x8 a[2];
#pragma unroll
    for (int t = 0; t < 2; ++t) {
      int r = row0 + t * 16 + lrow;
      uint4 tmp = {0u, 0u, 0u, 0u};
      if (r < M) tmp = *(const uint4*)(A16 + (size_t)r * HH + ks * 32 + lk);
      a[t] = __builtin_bit_cast(bf16x8, tmp);
    }
#pragma unroll
    for (int n = 0; n < 8; ++n) {
      bf16x8 b = __builtin_bit_cast(bf16x8, *(const uint4*)&Wt[n * 16 + lrow][ks * 32 + lk]);
      acc[0][n] = __builtin_amdgcn_mfma_f32_16x16x32_bf16(b, a[0], acc[0][n], 0, 0, 0);
      acc[1][n] = __builtin_amdgcn_mfma_f32_16x16x32_bf16(b, a[1], acc[1][n], 0, 0, 0);
    }
  }

  // epilogue 1 -> LDS tile (bias, no relu)
  {
    float4 b4[8];
#pragma unroll
    for (int n = 0; n < 8; ++n) b4[n] = *(const float4*)(ba + n * 16 + quad * 4);
#pragma unroll
    for (int t = 0; t < 2; ++t) {
      int trow = trow0 + t * 16 + lrow;
#pragma unroll
      for (int n = 0; n < 8; ++n) {
        uint2 o;
        o.x = f2b(acc[t][n][0] + b4[n].x) | (f2b(acc[t][n][1] + b4[n].y) << 16);
        o.y = f2b(acc[t][n][2] + b4[n].z) | (f2b(acc[t][n][3] + b4[n].w) << 16);
        *(uint2*)&tile[trow][n * 16 + quad * 4] = o;
      }
    }
  }
  __syncthreads();
  stage_w(Wt, Wb, tid);
#pragma unroll
  for (int t = 0; t < 2; ++t)
#pragma unroll
    for (int n = 0; n < 8; ++n)
      acc[t][n] = (floatx4){0.f, 0.f, 0.f, 0.f};
  __syncthreads();

  // phase 2: LDS tile A -> C2
#pragma unroll
  for (int ks = 0; ks < 4; ++ks) {
    bf16x8 a[2];
#pragma unroll
    for (int t = 0; t < 2; ++t)
      a[t] = __builtin_bit_cast(bf16x8,
               *(const uint4*)&tile[trow0 + t * 16 + lrow][ks * 32 + lk]);
#pragma unroll
    for (int n = 0; n < 8; ++n) {
      bf16x8 b = __builtin_bit_cast(bf16x8, *(const uint4*)&Wt[n * 16 + lrow][ks * 32 + lk]);
      acc[0][n] = __builtin_amdgcn_mfma_f32_16x16x32_bf16(b, a[0], acc[0][n], 0, 0, 0);
      acc[1][n] = __builtin_amdgcn_mfma_f32_16x16x32_bf16(b, a[1], acc[1][n], 0, 0, 0);
    }
  }

  // epilogue 2 -> global (bias, scale, no relu)
  {
    float4 b4[8];
#pragma unroll
    for (int n = 0; n < 8; ++n) b4[n] = *(const float4*)(bb + n * 16 + quad * 4);
#pragma unroll
    for (int t = 0; t < 2; ++t) {
      int row = row0 + t * 16 + lrow;
      if (row < M) {
        float sc = scale ? scale[row] : 1.0f;
        uint16_t* orow = Out + (size_t)row * HH;
#pragma unroll
        for (int n = 0; n < 8; ++n) {
          float v0 = (acc[t][n][0] + b4[n].x) * sc;
          float v1 = (acc[t][n][1] + b4[n].y) * sc;
          float v2 = (acc[t][n][2] + b4[n].z) * sc;
          float v3 = (acc[t][n][3] + b4[n].w) * sc;
          uint2 o;
          o.x = f2b(v0) | (f2b(v1) << 16);
          o.y = f2b(v2) | (f2b(v3) << 16);
          *(uint2*)(orow + n * 16 + quad * 4) = o;
        }
      }
    }
  }
}

// ================= aggregation: pre-scaled rows, pure gather-sum, unroll-4 =================
__global__ __launch_bounds__(256) void k_agg(
    const uint16_t* __restrict__ hw2, const int* __restrict__ off,
    const int* __restrict__ csrs, const float* __restrict__ inv,
    const int* __restrict__ order,
    uint16_t* __restrict__ hout, int do_relu)
{
  int slot = blockIdx.x * 16 + (threadIdx.x >> 4);
  if (slot >= NN) return;
  int node = order[slot];
  int c = (threadIdx.x & 15) * 8;   // 8 channels = 16 B per lane

  uint4 sv = *(const uint4*)(hw2 + (size_t)node * HH + c);
  float a[8] = {0.f, 0.f, 0.f, 0.f, 0.f, 0.f, 0.f, 0.f};
  addrow(a, sv);                    // self term (already inv[node]-scaled)

  int e0 = off[node], e1 = off[node + 1];
  int e = e0;
  for (; e + 4 <= e1; e += 4) {
    int s0 = csrs[e + 0], s1 = csrs[e + 1], s2 = csrs[e + 2], s3 = csrs[e + 3];
    uint4 v0 = *(const uint4*)(hw2 + (size_t)s0 * HH + c);
    uint4 v1 = *(const uint4*)(hw2 + (size_t)s1 * HH + c);
    uint4 v2 = *(const uint4*)(hw2 + (size_t)s2 * HH + c);
    uint4 v3 = *(const uint4*)(hw2 + (size_t)s3 * HH + c);
    addrow(a, v0); addrow(a, v1); addrow(a, v2); addrow(a, v3);
  }
  for (; e < e1; ++e) {
    int s = csrs[e];
    uint4 v = *(const uint4*)(hw2 + (size_t)s * HH + c);
    addrow(a, v);
  }
  float invd = inv[node];
#pragma unroll
  for (int j = 0; j < 8; ++j) {
    a[j] *= invd;
    if (do_relu) a[j] = fmaxf(a[j], 0.f);
  }
  uint4 o;
  o.x = f2b(a[0]) | (f2b(a[1]) << 16);
  o.y = f2b(a[2]) | (f2b(a[3]) << 16);
  o.z = f2b(a[4]) | (f2b(a[5]) << 16);
  o.w = f2b(a[6]) | (f2b(a[7]) << 16);
  *(uint4*)(hout + (size_t)node * HH + c) = o;
}

// ================= fused pool + decoder: one block per graph, zero atomics =================
__global__ __launch_bounds__(256) void k_pooldec(
    const uint16_t* __restrict__ h, const int* __restrict__ gstart,
    const float* __restrict__ w1, const float* __restrict__ b1,
    const float* __restrict__ w2, const float* __restrict__ b2,
    float* __restrict__ out)
{
  __shared__ float red[16][132];   // +4 pad
  __shared__ float p[128], tmpv[128];
  int g = blockIdx.x;
  int tid = threadIdx.x;
  int slot = tid >> 4;
  int c = (tid & 15) * 8;

  int r0 = gstart[g], r1 = gstart[g + 1];
  float a[8] = {0.f, 0.f, 0.f, 0.f, 0.f, 0.f, 0.f, 0.f};
  for (int r = r0 + slot; r < r1; r += 16) {
    uint4 v = *(const uint4*)(h + (size_t)r * HH + c);
    a[0] += b2f(v.x & 0xFFFFu); a[1] += b2f(v.x >> 16);
    a[2] += b2f(v.y & 0xFFFFu); a[3] += b2f(v.y >> 16);
    a[4] += b2f(v.z & 0xFFFFu); a[5] += b2f(v.z >> 16);
    a[6] += b2f(v.w & 0xFFFFu); a[7] += b2f(v.w >> 16);
  }
  *(float4*)&red[slot][c]     = make_float4(a[0], a[1], a[2], a[3]);
  *(float4*)&red[slot][c + 4] = make_float4(a[4], a[5], a[6], a[7]);
  __syncthreads();
  if (tid < 128) {
    float s = 0.f;
#pragma unroll
    for (int k = 0; k < 16; ++k) s += red[k][tid];
    p[tid] = s;
  }
  __syncthreads();
  if (tid < 128) {
    float acc1 = b1[tid];
    for (int k = 0; k < 128; ++k) acc1 += p[k] * w1[k * 128 + tid];
    tmpv[tid] = fmaxf(acc1, 0.f);
  }
  __syncthreads();
  if (tid < 10) {
    float o = b2[tid];
    for (int k = 0; k < 128; ++k) o += tmpv[k] * w2[k * 10 + tid];
    out[g * 10 + tid] = o;
  }
}

extern "C" void kernel_launch(void* const* d_in, const int* in_sizes, int n_in,
                              void* d_out, int out_size, void* d_ws, size_t ws_size,
                              hipStream_t stream) {
  const float* x       = (const float*)d_in[0];
  const int*   eidx    = (const int*)d_in[1];
  const int*   src     = eidx;            // edge_index[0]
  const int*   dst     = eidx + NE;       // edge_index[1]
  const int*   batch   = (const int*)d_in[3];
  const float* enc_w1  = (const float*)d_in[4];
  const float* enc_b1  = (const float*)d_in[5];
  const float* enc_w2  = (const float*)d_in[6];
  const float* enc_b2  = (const float*)d_in[7];
  const float* conv_w  = (const float*)d_in[8];
  const float* conv_b  = (const float*)d_in[9];
  const float* dec_w1  = (const float*)d_in[10];
  const float* dec_b1  = (const float*)d_in[11];
  const float* dec_w2  = (const float*)d_in[12];
  const float* dec_b2  = (const float*)d_in[13];
  float* out = (float*)d_out;

  char* ws = (char*)d_ws;
  size_t o = 0;
  auto alloc = [&](size_t bytes) -> char* {
    char* p = ws + o;
    o += (bytes + 255) & ~(size_t)255;
    return p;
  };
  int*      off     = (int*)alloc((size_t)(NN + 1) * 4);
  int*      csrs    = (int*)alloc((size_t)NE * 4);
  float*    inv     = (float*)alloc((size_t)NN * 4);
  int*      blkcntA = (int*)alloc((size_t)NBLK * NB * 4);
  int*      poffA   = (int*)alloc((size_t)NBLK * NB * 4);
  int*      blkcntB = (int*)alloc((size_t)NBLK * NB * 4);
  int*      poffB   = (int*)alloc((size_t)NBLK * NB * 4);
  int*      gbaseA  = (int*)alloc((size_t)(NB + 1) * 4);
  int*      gbaseB  = (int*)alloc((size_t)(NB + 1) * 4);
  int*      dhist2  = (int*)alloc((size_t)NB * 64 * 4);
  int*      dcur    = (int*)alloc(64 * 4);
  int*      order   = (int*)alloc((size_t)NN * 4);
  int*      gstart  = (int*)alloc((size_t)(NG + 1) * 4);
  uint16_t* buf0    = (uint16_t*)alloc((size_t)NN * HH * 2);
  uint16_t* buf1    = (uint16_t*)alloc((size_t)NN * HH * 2);
  uint2*    pairsA  = (uint2*)buf1;                          // 12.8 MB, dead before encoder
  uint32_t* pairB   = (uint32_t*)((char*)buf1 + (size_t)NE * 8);  // +6.4 MB, still < 25.6 MB

  // CSR build: sort by src-bucket, then stable by dst-bucket, then per-bucket by dst node
  k_cntA<<<dim3(NBLK), dim3(256), 0, stream>>>(src, blkcntA);
  k_scan<<<dim3(1), dim3(256), 0, stream>>>(blkcntA, poffA, gbaseA, off, 0);
  k_placeA<<<dim3(NBLK), dim3(256), 0, stream>>>(src, dst, poffA, gbaseA, pairsA);
  k_cntB<<<dim3(NBLK), dim3(256), 0, stream>>>(pairsA, blkcntB);
  k_scan<<<dim3(1), dim3(256), 0, stream>>>(blkcntB, poffB, gbaseB, off, 1);
  k_placeB<<<dim3(NBLK), dim3(256), 0, stream>>>(pairsA, poffB, gbaseB, pairB);
  k_bucket_sort<<<dim3(NB), dim3(256), 0, stream>>>(pairB, gbaseB, batch, off, inv, csrs,
                                                    dhist2, gstart);

  // degree-LPT order
  const int NBK = (NN + 255) / 256;
  k_dscan<<<dim3(1), dim3(64), 0, stream>>>(dhist2, dcur);
  k_dplace<<<dim3(NBK), dim3(256), 0, stream>>>(off, dcur, order);

  // encoder GEMM1 (fp32 x), then fused [enc2 + conv0 + prescale]
  const int GB = (NN + 127) / 128;   // 782
  k_gemm<<<dim3(GB), dim3(256), 0, stream>>>(nullptr, x, enc_w1, enc_b1, nullptr, buf1, NN, 1);
  k_gemm_dual<<<dim3(GB), dim3(256), 0, stream>>>(buf1, enc_w2, enc_b2,
                                                  conv_w + 0 * 16384, conv_b + 0,
                                                  inv, buf0, NN);

  // GCN layers: agg (pure gather-sum) alternating with prescaled conv GEMMs
  const int AB = (NN + 15) / 16;   // 6250
  k_agg <<<dim3(AB), dim3(256), 0, stream>>>(buf0, off, csrs, inv, order, buf1, 1);
  k_gemm<<<dim3(GB), dim3(256), 0, stream>>>(buf1, nullptr, conv_w + 1 * 16384, conv_b + 128, inv, buf0, NN, 0);
  k_agg <<<dim3(AB), dim3(256), 0, stream>>>(buf0, off, csrs, inv, order, buf1, 1);
  k_gemm<<<dim3(GB), dim3(256), 0, stream>>>(buf1, nullptr, conv_w + 2 * 16384, conv_b + 256, inv, buf0, NN, 0);
  k_agg <<<dim3(AB), dim3(256), 0, stream>>>(buf0, off, csrs, inv, order, buf1, 0);

  // fused pool + decoder
  k_pooldec<<<dim3(NG), dim3(256), 0, stream>>>(buf1, gstart, dec_w1, dec_b1, dec_w2, dec_b2, out);
}